// Round 1
// baseline (289.167 us; speedup 1.0000x reference)
//
#include <hip/hip_runtime.h>
#include <hip/hip_bf16.h>

// ---------------- problem constants ----------------
#define SEQ   4096
#define EMB   1024
#define NH    8
#define HD    128
#define NW    8
#define NSLOT 15   // distinct gathered positions: 0..10, S-4..S-1

typedef __attribute__((ext_vector_type(8))) short bf16x8;
typedef __attribute__((ext_vector_type(4))) float f32x4;
typedef __attribute__((ext_vector_type(8))) unsigned short ushort8v;

// slot tables for the 7 boundary rows (t = 0,1,2,3, S-3, S-2, S-1)
// slot s: s<11 -> absolute pos s ; s>=11 -> absolute pos S-4+(s-11)
__device__ __constant__ int SPECIAL[7][8] = {
    {0, 1, 2, 3, 4, 5, 6, 7},          // t=0
    {14, 0, 1, 2, 3, 6, 7, 8},         // t=1
    {13, 14, 0, 1, 2, 3, 8, 9},        // t=2
    {12, 13, 14, 0, 1, 2, 3, 10},      // t=3
    {11, 11, 12, 13, 14, 0, 1, 2},     // t=S-3
    {12, 11, 11, 12, 13, 14, 0, 1},    // t=S-2
    {13, 12, 11, 11, 12, 13, 14, 0},   // t=S-1
};

__device__ __forceinline__ unsigned short f2bf(float x) {
    unsigned int u = __float_as_uint(x);
    return (unsigned short)((u + 0x7FFFu + ((u >> 16) & 1u)) >> 16);
}

__device__ __forceinline__ ushort8v pack8(float4 a, float4 b) {
    ushort8v r;
    r[0] = f2bf(a.x); r[1] = f2bf(a.y); r[2] = f2bf(a.z); r[3] = f2bf(a.w);
    r[4] = f2bf(b.x); r[5] = f2bf(b.y); r[6] = f2bf(b.z); r[7] = f2bf(b.w);
    return r;
}

// ---------------- small k/v projection: only NSLOT rows per (b, kv) ----------------
// grid: B*2*NSLOT blocks, 256 threads. Each block computes one full projected row (1024 feats).
__global__ __launch_bounds__(256) void proj_kv_small(
    const float* __restrict__ k, const float* __restrict__ v,
    const float* __restrict__ ipw, const float* __restrict__ ipb,
    float* __restrict__ kvp) {
    int blk  = blockIdx.x;
    int slot = blk % NSLOT;
    int kv   = (blk / NSLOT) & 1;
    int b    = blk / (2 * NSLOT);
    int j    = (slot < 11) ? slot : (SEQ - 4 + (slot - 11));

    const float* x  = (kv ? v : k) + ((size_t)(b * SEQ + j)) * EMB;
    const float* Wm = ipw + (size_t)(1 + kv) * EMB * EMB;   // Wk or Wv, row-major (out, in)
    const float* bb = ipb + (size_t)(1 + kv) * EMB;
    float* outp     = kvp + ((size_t)((b * 2 + kv) * NSLOT + slot)) * EMB;

    __shared__ __align__(16) float xs[EMB];
    int tid = threadIdx.x;
    *(float4*)&xs[tid * 4] = *(const float4*)&x[tid * 4];
    __syncthreads();

    int f0 = tid * 4;
    float acc0 = 0.f, acc1 = 0.f, acc2 = 0.f, acc3 = 0.f;
    for (int kk = 0; kk < EMB; kk += 4) {
        float4 xv = *(const float4*)&xs[kk];
        float4 w0 = *(const float4*)&Wm[(size_t)(f0 + 0) * EMB + kk];
        float4 w1 = *(const float4*)&Wm[(size_t)(f0 + 1) * EMB + kk];
        float4 w2 = *(const float4*)&Wm[(size_t)(f0 + 2) * EMB + kk];
        float4 w3 = *(const float4*)&Wm[(size_t)(f0 + 3) * EMB + kk];
        acc0 += xv.x * w0.x + xv.y * w0.y + xv.z * w0.z + xv.w * w0.w;
        acc1 += xv.x * w1.x + xv.y * w1.y + xv.z * w1.z + xv.w * w1.w;
        acc2 += xv.x * w2.x + xv.y * w2.y + xv.z * w2.z + xv.w * w2.w;
        acc3 += xv.x * w3.x + xv.y * w3.y + xv.z * w3.z + xv.w * w3.w;
    }
    float4 r;
    r.x = acc0 + bb[f0 + 0];
    r.y = acc1 + bb[f0 + 1];
    r.z = acc2 + bb[f0 + 2];
    r.w = acc3 + bb[f0 + 3];
    *(float4*)&outp[f0] = r;
}

// ---------------- bf16 MFMA GEMM:  C[M,N] = A[M,K] @ W[N,K]^T + bias[N]  (fp32 in/out) ----------------
#define BM 128
#define BN 128
#define BKK 32
#define KPAD 40   // padded bf16 row stride (80B) -> 2-way LDS bank aliasing only (free)

__global__ __launch_bounds__(256) void gemm_bt(
    const float* __restrict__ A, const float* __restrict__ Wt,
    const float* __restrict__ bias, float* __restrict__ C,
    int M, int N, int K) {
    __shared__ __align__(16) unsigned short As[BM * KPAD];
    __shared__ __align__(16) unsigned short Bs[BN * KPAD];

    int tid  = threadIdx.x;
    int nbt  = N / BN;
    int mb0  = (blockIdx.x / nbt) * BM;
    int nb0  = (blockIdx.x % nbt) * BN;
    int lane = tid & 63;
    int wv   = tid >> 6;          // wave 0..3  (2x2 wave grid)
    int wr   = (wv >> 1) * 64;    // wave row offset
    int wc   = (wv & 1) * 64;     // wave col offset

    // staging coords: 2 threads per row, 16 k each
    int srow  = tid >> 1;
    int skseg = (tid & 1) * 16;
    const float* Arow = A  + (size_t)(mb0 + srow) * K + skseg;
    const float* Wrow = Wt + (size_t)(nb0 + srow) * K + skseg;

    f32x4 acc[4][4] = {};

    int kgrp = (lane >> 4) * 8;          // k-base of this lane's fragment
    int rA   = wr + (lane & 15);
    int rB   = wc + (lane & 15);

    for (int kb = 0; kb < K; kb += BKK) {
        float4 a0 = *(const float4*)(Arow + kb);
        float4 a1 = *(const float4*)(Arow + kb + 4);
        float4 a2 = *(const float4*)(Arow + kb + 8);
        float4 a3 = *(const float4*)(Arow + kb + 12);
        float4 b0 = *(const float4*)(Wrow + kb);
        float4 b1 = *(const float4*)(Wrow + kb + 4);
        float4 b2 = *(const float4*)(Wrow + kb + 8);
        float4 b3 = *(const float4*)(Wrow + kb + 12);

        __syncthreads();   // previous iteration's reads complete
        *(ushort8v*)&As[srow * KPAD + skseg]     = pack8(a0, a1);
        *(ushort8v*)&As[srow * KPAD + skseg + 8] = pack8(a2, a3);
        *(ushort8v*)&Bs[srow * KPAD + skseg]     = pack8(b0, b1);
        *(ushort8v*)&Bs[srow * KPAD + skseg + 8] = pack8(b2, b3);
        __syncthreads();

        bf16x8 afr[4], bfr[4];
#pragma unroll
        for (int m = 0; m < 4; m++)
            afr[m] = *(const bf16x8*)&As[(rA + m * 16) * KPAD + kgrp];
#pragma unroll
        for (int n = 0; n < 4; n++)
            bfr[n] = *(const bf16x8*)&Bs[(rB + n * 16) * KPAD + kgrp];
#pragma unroll
        for (int m = 0; m < 4; m++)
#pragma unroll
            for (int n = 0; n < 4; n++)
                acc[m][n] = __builtin_amdgcn_mfma_f32_16x16x32_bf16(
                    afr[m], bfr[n], acc[m][n], 0, 0, 0);
    }

    // epilogue: C/D layout col=lane&15, row=(lane>>4)*4+reg   [verified m89/m91]
    int rowb = mb0 + wr + ((lane >> 4) * 4);
    int colb = nb0 + wc + (lane & 15);
#pragma unroll
    for (int n = 0; n < 4; n++) {
        int col = colb + n * 16;
        float bn = bias[col];
#pragma unroll
        for (int m = 0; m < 4; m++) {
#pragma unroll
            for (int r = 0; r < 4; r++) {
                int row = rowb + m * 16 + r;
                C[(size_t)row * N + col] = acc[m][n][r] + bn;
            }
        }
    }
}

// ---------------- windowed attention (fp32): one wave per (b,t,h) ----------------
__global__ __launch_bounds__(256) void attn_win(
    const float* __restrict__ qp, const float* __restrict__ kvp,
    float* __restrict__ o) {
    int tid  = threadIdx.x;
    int wid  = blockIdx.x * 4 + (tid >> 6);
    int lane = tid & 63;
    int h = wid & 7;
    int t = (wid >> 3) & (SEQ - 1);
    int b = wid >> 15;

    int w   = lane >> 3;   // window position this lane scores
    int seg = lane & 7;    // 16-elem segment of the d=128 dot

    bool interior = (t >= 4) && (t <= SEQ - 4);
    int c = 0;
    if (!interior) c = (t < 4) ? t : (t - (SEQ - 3) + 4);

    int myslot = interior ? ((w < 4) ? (11 + w) : (w - 4)) : SPECIAL[c][w];

    const float* qrow = qp + ((size_t)(b * SEQ + t)) * EMB + h * HD + seg * 16;
    const float* krow = kvp + ((size_t)(b * 2 * NSLOT + myslot)) * EMB + h * HD + seg * 16;

    float partial = 0.f;
#pragma unroll
    for (int i = 0; i < 16; i += 4) {
        float4 qv = *(const float4*)(qrow + i);
        float4 kv = *(const float4*)(krow + i);
        partial += qv.x * kv.x + qv.y * kv.y + qv.z * kv.z + qv.w * kv.w;
    }
    // reduce over the 8 lanes of this window-group
    partial += __shfl_xor(partial, 1, 64);
    partial += __shfl_xor(partial, 2, 64);
    partial += __shfl_xor(partial, 4, 64);
    float score = partial * 0.08838834764831845f;   // 1/sqrt(128)

    // gather all 8 scores into every lane
    float sc[8];
#pragma unroll
    for (int j = 0; j < 8; j++) sc[j] = __shfl(score, (j << 3) | seg, 64);

    float mx = sc[0];
#pragma unroll
    for (int j = 1; j < 8; j++) mx = fmaxf(mx, sc[j]);
    float ssum = 0.f;
#pragma unroll
    for (int j = 0; j < 8; j++) { sc[j] = expf(sc[j] - mx); ssum += sc[j]; }
    float inv = 1.0f / ssum;

    // each lane produces 2 output elements at d = lane*2
    float2 accv = make_float2(0.f, 0.f);
#pragma unroll
    for (int j = 0; j < 8; j++) {
        int sj = interior ? ((j < 4) ? (11 + j) : (j - 4)) : SPECIAL[c][j];
        const float2 vv = *(const float2*)(kvp +
            ((size_t)((b * 2 + 1) * NSLOT + sj)) * EMB + h * HD + lane * 2);
        accv.x += sc[j] * vv.x;
        accv.y += sc[j] * vv.y;
    }
    accv.x *= inv;
    accv.y *= inv;
    *(float2*)(o + ((size_t)(b * SEQ + t)) * EMB + h * HD + lane * 2) = accv;
}

// ---------------- launcher ----------------
extern "C" void kernel_launch(void* const* d_in, const int* in_sizes, int n_in,
                              void* d_out, int out_size, void* d_ws, size_t ws_size,
                              hipStream_t stream) {
    const float* q    = (const float*)d_in[0];
    const float* k    = (const float*)d_in[1];
    const float* v    = (const float*)d_in[2];
    const float* ipw  = (const float*)d_in[3];
    const float* ipb  = (const float*)d_in[4];
    const float* outw = (const float*)d_in[5];
    const float* outb = (const float*)d_in[6];
    float* out = (float*)d_out;

    int Bb = in_sizes[0] / (SEQ * EMB);     // batch (=2)
    int M  = Bb * SEQ;                      // 8192 rows

    float* qp  = (float*)d_ws;                       // M x EMB fp32
    float* o   = qp + (size_t)M * EMB;               // M x EMB fp32
    float* kvp = o + (size_t)M * EMB;                // B*2*NSLOT x EMB fp32

    // 1. project only the NSLOT needed k/v rows per batch
    proj_kv_small<<<dim3(Bb * 2 * NSLOT), dim3(256), 0, stream>>>(k, v, ipw, ipb, kvp);
    // 2. q projection (full GEMM)
    gemm_bt<<<dim3((M / BM) * (EMB / BN)), dim3(256), 0, stream>>>(
        q, ipw, ipb, qp, M, EMB, EMB);
    // 3. windowed attention
    attn_win<<<dim3(Bb * SEQ * NH / 4), dim3(256), 0, stream>>>(qp, kvp, o);
    // 4. output projection
    gemm_bt<<<dim3((M / BM) * (EMB / BN)), dim3(256), 0, stream>>>(
        o, outw, outb, out, M, EMB, EMB);
}

// Round 2
// 181.055 us; speedup vs baseline: 1.5971x; 1.5971x over previous
//
#include <hip/hip_runtime.h>
#include <hip/hip_bf16.h>

// ---------------- problem constants ----------------
#define SEQ   4096
#define EMB   1024
#define NH    8
#define HD    128
#define NW    8
#define NSLOT 15   // distinct gathered positions: 0..10, S-4..S-1

typedef __attribute__((ext_vector_type(8))) short bf16x8;
typedef __attribute__((ext_vector_type(4))) float f32x4;
typedef __attribute__((ext_vector_type(8))) unsigned short ushort8v;

// slot tables for the 7 boundary rows (t = 0,1,2,3, S-3, S-2, S-1)
// slot s: s<11 -> absolute pos s ; s>=11 -> absolute pos S-4+(s-11)
__device__ __constant__ int SPECIAL[7][8] = {
    {0, 1, 2, 3, 4, 5, 6, 7},          // t=0
    {14, 0, 1, 2, 3, 6, 7, 8},         // t=1
    {13, 14, 0, 1, 2, 3, 8, 9},        // t=2
    {12, 13, 14, 0, 1, 2, 3, 10},      // t=3
    {11, 11, 12, 13, 14, 0, 1, 2},     // t=S-3
    {12, 11, 11, 12, 13, 14, 0, 1},    // t=S-2
    {13, 12, 11, 11, 12, 13, 14, 0},   // t=S-1
};

__device__ __forceinline__ unsigned short f2bf(float x) {
    unsigned int u = __float_as_uint(x);
    return (unsigned short)((u + 0x7FFFu + ((u >> 16) & 1u)) >> 16);
}

__device__ __forceinline__ ushort8v pack8(float4 a, float4 b) {
    ushort8v r;
    r[0] = f2bf(a.x); r[1] = f2bf(a.y); r[2] = f2bf(a.z); r[3] = f2bf(a.w);
    r[4] = f2bf(b.x); r[5] = f2bf(b.y); r[6] = f2bf(b.z); r[7] = f2bf(b.w);
    return r;
}

// ---------------- small k/v projection, v2 ----------------
// grid: 4 (b,kv) x 64 feature-chunks = 256 blocks, 256 threads.
// Block stages its 15 gathered x-rows in LDS (60 KB); thread t<240 computes
// one (row, feat) dot over K=1024. Weight read once per (batch, kv): 16 MB total.
__global__ __launch_bounds__(256) void proj_kv_small(
    const float* __restrict__ k, const float* __restrict__ v,
    const float* __restrict__ ipw, const float* __restrict__ ipb,
    float* __restrict__ kvp) {
    int fc  = blockIdx.x & 63;         // feature chunk (16 feats)
    int bkv = blockIdx.x >> 6;         // 0..3
    int kv  = bkv & 1;
    int b   = bkv >> 1;

    const float* x0 = (kv ? v : k) + (size_t)b * SEQ * EMB;
    const float* Wm = ipw + (size_t)(1 + kv) * EMB * EMB;   // Wk or Wv (out, in)
    const float* bb = ipb + (size_t)(1 + kv) * EMB;

    __shared__ __align__(16) float xs[NSLOT][EMB];          // 60 KB
    int tid = threadIdx.x;
#pragma unroll
    for (int i = 0; i < NSLOT; i++) {
        int pos = (i < 11) ? i : (SEQ - 4 + (i - 11));
        *(float4*)&xs[i][tid * 4] = *(const float4*)&x0[(size_t)pos * EMB + tid * 4];
    }
    __syncthreads();

    if (tid < 240) {
        int row  = tid >> 4;           // slot 0..14
        int feat = fc * 16 + (tid & 15);
        const float* wrow = Wm + (size_t)feat * EMB;
        float acc = 0.f;
        for (int kk = 0; kk < EMB; kk += 4) {
            float4 xv = *(const float4*)&xs[row][kk];
            float4 wv = *(const float4*)&wrow[kk];
            acc += xv.x * wv.x + xv.y * wv.y + xv.z * wv.z + xv.w * wv.w;
        }
        kvp[((size_t)((b * 2 + kv) * NSLOT + row)) * EMB + feat] = acc + bb[feat];
    }
}

// ---------------- bf16 MFMA GEMM:  C[M,N] = A[M,K] @ W[N,K]^T + bias[N]  (fp32 in/out) ----------------
#define BM 128
#define BN 128
#define BKK 32
#define KPAD 40   // padded bf16 row stride (80B) -> 2-way LDS bank aliasing only (free)

__global__ __launch_bounds__(256) void gemm_bt(
    const float* __restrict__ A, const float* __restrict__ Wt,
    const float* __restrict__ bias, float* __restrict__ C,
    int M, int N, int K) {
    __shared__ __align__(16) unsigned short As[BM * KPAD];
    __shared__ __align__(16) unsigned short Bs[BN * KPAD];

    int tid  = threadIdx.x;
    int nbt  = N / BN;
    int mb0  = (blockIdx.x / nbt) * BM;
    int nb0  = (blockIdx.x % nbt) * BN;
    int lane = tid & 63;
    int wv   = tid >> 6;          // wave 0..3  (2x2 wave grid)
    int wr   = (wv >> 1) * 64;    // wave row offset
    int wc   = (wv & 1) * 64;     // wave col offset

    // staging coords: 2 threads per row, 16 k each
    int srow  = tid >> 1;
    int skseg = (tid & 1) * 16;
    const float* Arow = A  + (size_t)(mb0 + srow) * K + skseg;
    const float* Wrow = Wt + (size_t)(nb0 + srow) * K + skseg;

    f32x4 acc[4][4] = {};

    int kgrp = (lane >> 4) * 8;          // k-base of this lane's fragment
    int rA   = wr + (lane & 15);
    int rB   = wc + (lane & 15);

    for (int kb = 0; kb < K; kb += BKK) {
        float4 a0 = *(const float4*)(Arow + kb);
        float4 a1 = *(const float4*)(Arow + kb + 4);
        float4 a2 = *(const float4*)(Arow + kb + 8);
        float4 a3 = *(const float4*)(Arow + kb + 12);
        float4 b0 = *(const float4*)(Wrow + kb);
        float4 b1 = *(const float4*)(Wrow + kb + 4);
        float4 b2 = *(const float4*)(Wrow + kb + 8);
        float4 b3 = *(const float4*)(Wrow + kb + 12);

        __syncthreads();   // previous iteration's reads complete
        *(ushort8v*)&As[srow * KPAD + skseg]     = pack8(a0, a1);
        *(ushort8v*)&As[srow * KPAD + skseg + 8] = pack8(a2, a3);
        *(ushort8v*)&Bs[srow * KPAD + skseg]     = pack8(b0, b1);
        *(ushort8v*)&Bs[srow * KPAD + skseg + 8] = pack8(b2, b3);
        __syncthreads();

        bf16x8 afr[4], bfr[4];
#pragma unroll
        for (int m = 0; m < 4; m++)
            afr[m] = *(const bf16x8*)&As[(rA + m * 16) * KPAD + kgrp];
#pragma unroll
        for (int n = 0; n < 4; n++)
            bfr[n] = *(const bf16x8*)&Bs[(rB + n * 16) * KPAD + kgrp];
#pragma unroll
        for (int m = 0; m < 4; m++)
#pragma unroll
            for (int n = 0; n < 4; n++)
                acc[m][n] = __builtin_amdgcn_mfma_f32_16x16x32_bf16(
                    afr[m], bfr[n], acc[m][n], 0, 0, 0);
    }

    // epilogue: C/D layout col=lane&15, row=(lane>>4)*4+reg   [verified m89/m91]
    int rowb = mb0 + wr + ((lane >> 4) * 4);
    int colb = nb0 + wc + (lane & 15);
#pragma unroll
    for (int n = 0; n < 4; n++) {
        int col = colb + n * 16;
        float bn = bias[col];
#pragma unroll
        for (int m = 0; m < 4; m++) {
#pragma unroll
            for (int r = 0; r < 4; r++) {
                int row = rowb + m * 16 + r;
                C[(size_t)row * N + col] = acc[m][n][r] + bn;
            }
        }
    }
}

// ---------------- windowed attention (fp32): one wave per (b,t,h) ----------------
__global__ __launch_bounds__(256) void attn_win(
    const float* __restrict__ qp, const float* __restrict__ kvp,
    float* __restrict__ o) {
    int tid  = threadIdx.x;
    int wid  = blockIdx.x * 4 + (tid >> 6);
    int lane = tid & 63;
    int h = wid & 7;
    int t = (wid >> 3) & (SEQ - 1);
    int b = wid >> 15;

    int w   = lane >> 3;   // window position this lane scores
    int seg = lane & 7;    // 16-elem segment of the d=128 dot

    bool interior = (t >= 4) && (t <= SEQ - 4);
    int c = 0;
    if (!interior) c = (t < 4) ? t : (t - (SEQ - 3) + 4);

    int myslot = interior ? ((w < 4) ? (11 + w) : (w - 4)) : SPECIAL[c][w];

    const float* qrow = qp + ((size_t)(b * SEQ + t)) * EMB + h * HD + seg * 16;
    const float* krow = kvp + ((size_t)(b * 2 * NSLOT + myslot)) * EMB + h * HD + seg * 16;

    float partial = 0.f;
#pragma unroll
    for (int i = 0; i < 16; i += 4) {
        float4 qv = *(const float4*)(qrow + i);
        float4 kv = *(const float4*)(krow + i);
        partial += qv.x * kv.x + qv.y * kv.y + qv.z * kv.z + qv.w * kv.w;
    }
    // reduce over the 8 lanes of this window-group
    partial += __shfl_xor(partial, 1, 64);
    partial += __shfl_xor(partial, 2, 64);
    partial += __shfl_xor(partial, 4, 64);
    float score = partial * 0.08838834764831845f;   // 1/sqrt(128)

    // gather all 8 scores into every lane
    float sc[8];
#pragma unroll
    for (int j = 0; j < 8; j++) sc[j] = __shfl(score, (j << 3) | seg, 64);

    float mx = sc[0];
#pragma unroll
    for (int j = 1; j < 8; j++) mx = fmaxf(mx, sc[j]);
    float ssum = 0.f;
#pragma unroll
    for (int j = 0; j < 8; j++) { sc[j] = expf(sc[j] - mx); ssum += sc[j]; }
    float inv = 1.0f / ssum;

    // each lane produces 2 output elements at d = lane*2
    float2 accv = make_float2(0.f, 0.f);
#pragma unroll
    for (int j = 0; j < 8; j++) {
        int sj = interior ? ((j < 4) ? (11 + j) : (j - 4)) : SPECIAL[c][j];
        const float2 vv = *(const float2*)(kvp +
            ((size_t)((b * 2 + 1) * NSLOT + sj)) * EMB + h * HD + lane * 2);
        accv.x += sc[j] * vv.x;
        accv.y += sc[j] * vv.y;
    }
    accv.x *= inv;
    accv.y *= inv;
    *(float2*)(o + ((size_t)(b * SEQ + t)) * EMB + h * HD + lane * 2) = accv;
}

// ---------------- launcher ----------------
extern "C" void kernel_launch(void* const* d_in, const int* in_sizes, int n_in,
                              void* d_out, int out_size, void* d_ws, size_t ws_size,
                              hipStream_t stream) {
    const float* q    = (const float*)d_in[0];
    const float* k    = (const float*)d_in[1];
    const float* v    = (const float*)d_in[2];
    const float* ipw  = (const float*)d_in[3];
    const float* ipb  = (const float*)d_in[4];
    const float* outw = (const float*)d_in[5];
    const float* outb = (const float*)d_in[6];
    float* out = (float*)d_out;

    int Bb = in_sizes[0] / (SEQ * EMB);     // batch (=2)
    int M  = Bb * SEQ;                      // 8192 rows

    float* qp  = (float*)d_ws;                       // M x EMB fp32
    float* o   = qp + (size_t)M * EMB;               // M x EMB fp32
    float* kvp = o + (size_t)M * EMB;                // B*2*NSLOT x EMB fp32

    // 1. project only the NSLOT needed k/v rows per batch (weights read once per (b,kv))
    proj_kv_small<<<dim3(Bb * 2 * 64), dim3(256), 0, stream>>>(k, v, ipw, ipb, kvp);
    // 2. q projection (full GEMM)
    gemm_bt<<<dim3((M / BM) * (EMB / BN)), dim3(256), 0, stream>>>(
        q, ipw, ipb, qp, M, EMB, EMB);
    // 3. windowed attention
    attn_win<<<dim3(Bb * SEQ * NH / 4), dim3(256), 0, stream>>>(qp, kvp, o);
    // 4. output projection
    gemm_bt<<<dim3((M / BM) * (EMB / BN)), dim3(256), 0, stream>>>(
        o, outw, outb, out, M, EMB, EMB);
}

// Round 3
// 163.605 us; speedup vs baseline: 1.7675x; 1.1067x over previous
//
#include <hip/hip_runtime.h>
#include <hip/hip_bf16.h>

// ---------------- problem constants ----------------
#define SEQ   4096
#define EMB   1024
#define NH    8
#define HD    128
#define NSLOT 15   // distinct gathered positions: 0..10, S-4..S-1

typedef __attribute__((ext_vector_type(8))) short bf16x8;
typedef __attribute__((ext_vector_type(4))) float f32x4;
typedef __attribute__((ext_vector_type(8))) unsigned short ushort8v;
typedef unsigned short ushort_t;

// slot tables for the 7 boundary rows (t = 0,1,2,3, S-3, S-2, S-1)
__device__ __constant__ int SPECIAL[7][8] = {
    {0, 1, 2, 3, 4, 5, 6, 7},          // t=0
    {14, 0, 1, 2, 3, 6, 7, 8},         // t=1
    {13, 14, 0, 1, 2, 3, 8, 9},        // t=2
    {12, 13, 14, 0, 1, 2, 3, 10},      // t=3
    {11, 11, 12, 13, 14, 0, 1, 2},     // t=S-3
    {12, 11, 11, 12, 13, 14, 0, 1},    // t=S-2
    {13, 12, 11, 11, 12, 13, 14, 0},   // t=S-1
};

__device__ __forceinline__ unsigned short f2bf(float x) {
    unsigned int u = __float_as_uint(x);
    return (unsigned short)((u + 0x7FFFu + ((u >> 16) & 1u)) >> 16);
}

__device__ __forceinline__ ushort8v pack8(float4 a, float4 b) {
    ushort8v r;
    r[0] = f2bf(a.x); r[1] = f2bf(a.y); r[2] = f2bf(a.z); r[3] = f2bf(a.w);
    r[4] = f2bf(b.x); r[5] = f2bf(b.y); r[6] = f2bf(b.z); r[7] = f2bf(b.w);
    return r;
}

// async global->LDS, 16B per lane; lds ptr must be wave-uniform
__device__ __forceinline__ void gld16(const ushort_t* g, ushort_t* l) {
    __builtin_amdgcn_global_load_lds(
        (const __attribute__((address_space(1))) unsigned int*)g,
        (__attribute__((address_space(3))) unsigned int*)l,
        16, 0, 0);
}

// ---------------- fp32 -> bf16 conversion (memory-bound) ----------------
__global__ __launch_bounds__(256) void cvt_f32_bf16(
    const float* __restrict__ src, ushort_t* __restrict__ dst, int n) {
    int i = (blockIdx.x * 256 + threadIdx.x) * 8;
    if (i < n) {
        float4 a = *(const float4*)&src[i];
        float4 b = *(const float4*)&src[i + 4];
        *(ushort8v*)&dst[i] = pack8(a, b);
    }
}

// ---------------- small k/v projection ----------------
// grid: 4 (b,kv) x 64 feature-chunks; block stages 15 gathered x-rows in LDS.
__global__ __launch_bounds__(256) void proj_kv_small(
    const float* __restrict__ k, const float* __restrict__ v,
    const float* __restrict__ ipw, const float* __restrict__ ipb,
    float* __restrict__ kvp) {
    int fc  = blockIdx.x & 63;
    int bkv = blockIdx.x >> 6;
    int kv  = bkv & 1;
    int b   = bkv >> 1;

    const float* x0 = (kv ? v : k) + (size_t)b * SEQ * EMB;
    const float* Wm = ipw + (size_t)(1 + kv) * EMB * EMB;
    const float* bb = ipb + (size_t)(1 + kv) * EMB;

    __shared__ __align__(16) float xs[NSLOT][EMB];
    int tid = threadIdx.x;
#pragma unroll
    for (int i = 0; i < NSLOT; i++) {
        int pos = (i < 11) ? i : (SEQ - 4 + (i - 11));
        *(float4*)&xs[i][tid * 4] = *(const float4*)&x0[(size_t)pos * EMB + tid * 4];
    }
    __syncthreads();

    if (tid < 240) {
        int row  = tid >> 4;
        int feat = fc * 16 + (tid & 15);
        const float* wrow = Wm + (size_t)feat * EMB;
        float acc = 0.f;
        for (int kk = 0; kk < EMB; kk += 4) {
            float4 xv = *(const float4*)&xs[row][kk];
            float4 wv = *(const float4*)&wrow[kk];
            acc += xv.x * wv.x + xv.y * wv.y + xv.z * wv.z + xv.w * wv.w;
        }
        kvp[((size_t)((b * 2 + kv) * NSLOT + row)) * EMB + feat] = acc + bb[feat];
    }
}

// ---------------- bf16 MFMA GEMM (m97 structure):  C[M,N] = A @ Wt^T + bias ----------------
// A: M x K bf16, Wt: N x K bf16, C: M x N fp32. global_load_lds width-16 staging.
#define BM 128
#define BN 128
#define BK 32

__global__ __launch_bounds__(256) void gemm_bt_bf16(
    const ushort_t* __restrict__ A, const ushort_t* __restrict__ Wt,
    const float* __restrict__ bias, float* __restrict__ C,
    int M, int N, int K) {
    __shared__ __align__(16) ushort_t As[BM * BK];   // 8 KB, linear (gld16 requirement)
    __shared__ __align__(16) ushort_t Bs[BN * BK];   // 8 KB

    int tid  = threadIdx.x;
    int nbt  = N / BN;
    int mb0  = (blockIdx.x / nbt) * BM;
    int nb0  = (blockIdx.x % nbt) * BN;
    int lane = tid & 63;
    int w    = tid >> 6;          // wave 0..3 (2x2 wave grid for compute)
    int wr   = (w >> 1) * 64;
    int wc   = (w & 1) * 64;

    // staging: wave w covers rows [w*32, w*32+32), 2 issues of 16 rows each.
    // lane l covers row (l>>2), k-seg (l&3)*8 within an issue.
    int sr0 = w * 32 + (lane >> 2);       // issue 0 row
    int kcol = (lane & 3) * 8;
    const ushort_t* asrc0 = A  + (size_t)(mb0 + sr0) * K + kcol;
    const ushort_t* asrc1 = A  + (size_t)(mb0 + sr0 + 16) * K + kcol;
    const ushort_t* bsrc0 = Wt + (size_t)(nb0 + sr0) * K + kcol;
    const ushort_t* bsrc1 = Wt + (size_t)(nb0 + sr0 + 16) * K + kcol;
    ushort_t* adst0 = &As[(w * 2 + 0) * 512];   // wave-uniform LDS bases
    ushort_t* adst1 = &As[(w * 2 + 1) * 512];
    ushort_t* bdst0 = &Bs[(w * 2 + 0) * 512];
    ushort_t* bdst1 = &Bs[(w * 2 + 1) * 512];

    f32x4 acc[4][4] = {};

    int kgrp = (lane >> 4) * 8;
    int rA   = wr + (lane & 15);
    int rB   = wc + (lane & 15);

    for (int kb = 0; kb < K; kb += BK) {
        __syncthreads();             // WAR: all waves done reading LDS
        gld16(asrc0 + kb, adst0);
        gld16(asrc1 + kb, adst1);
        gld16(bsrc0 + kb, bdst0);
        gld16(bsrc1 + kb, bdst1);
        __syncthreads();             // drains vmcnt -> tile visible

        bf16x8 afr[4], bfr[4];
#pragma unroll
        for (int m = 0; m < 4; m++)
            afr[m] = *(const bf16x8*)&As[(rA + m * 16) * BK + kgrp];
#pragma unroll
        for (int n = 0; n < 4; n++)
            bfr[n] = *(const bf16x8*)&Bs[(rB + n * 16) * BK + kgrp];
#pragma unroll
        for (int m = 0; m < 4; m++)
#pragma unroll
            for (int n = 0; n < 4; n++)
                acc[m][n] = __builtin_amdgcn_mfma_f32_16x16x32_bf16(
                    afr[m], bfr[n], acc[m][n], 0, 0, 0);
    }

    // epilogue: C/D layout col=lane&15, row=(lane>>4)*4+reg  [verified m89/m91]
    int rowb = mb0 + wr + ((lane >> 4) * 4);
    int colb = nb0 + wc + (lane & 15);
#pragma unroll
    for (int n = 0; n < 4; n++) {
        int col = colb + n * 16;
        float bn = bias[col];
#pragma unroll
        for (int m = 0; m < 4; m++) {
#pragma unroll
            for (int r = 0; r < 4; r++) {
                int row = rowb + m * 16 + r;
                C[(size_t)row * N + col] = acc[m][n][r] + bn;
            }
        }
    }
}

// ---------------- windowed attention (fp32 math, bf16 output) ----------------
__global__ __launch_bounds__(256) void attn_win(
    const float* __restrict__ qp, const float* __restrict__ kvp,
    ushort_t* __restrict__ o) {
    int tid  = threadIdx.x;
    int wid  = blockIdx.x * 4 + (tid >> 6);
    int lane = tid & 63;
    int h = wid & 7;
    int t = (wid >> 3) & (SEQ - 1);
    int b = wid >> 15;

    int w   = lane >> 3;
    int seg = lane & 7;

    bool interior = (t >= 4) && (t <= SEQ - 4);
    int c = 0;
    if (!interior) c = (t < 4) ? t : (t - (SEQ - 3) + 4);

    int myslot = interior ? ((w < 4) ? (11 + w) : (w - 4)) : SPECIAL[c][w];

    const float* qrow = qp + ((size_t)(b * SEQ + t)) * EMB + h * HD + seg * 16;
    const float* krow = kvp + ((size_t)(b * 2 * NSLOT + myslot)) * EMB + h * HD + seg * 16;

    float partial = 0.f;
#pragma unroll
    for (int i = 0; i < 16; i += 4) {
        float4 qv = *(const float4*)(qrow + i);
        float4 kv = *(const float4*)(krow + i);
        partial += qv.x * kv.x + qv.y * kv.y + qv.z * kv.z + qv.w * kv.w;
    }
    partial += __shfl_xor(partial, 1, 64);
    partial += __shfl_xor(partial, 2, 64);
    partial += __shfl_xor(partial, 4, 64);
    float score = partial * 0.08838834764831845f;   // 1/sqrt(128)

    float sc[8];
#pragma unroll
    for (int j = 0; j < 8; j++) sc[j] = __shfl(score, (j << 3) | seg, 64);

    float mx = sc[0];
#pragma unroll
    for (int j = 1; j < 8; j++) mx = fmaxf(mx, sc[j]);
    float ssum = 0.f;
#pragma unroll
    for (int j = 0; j < 8; j++) { sc[j] = expf(sc[j] - mx); ssum += sc[j]; }
    float inv = 1.0f / ssum;

    float2 accv = make_float2(0.f, 0.f);
#pragma unroll
    for (int j = 0; j < 8; j++) {
        int sj = interior ? ((j < 4) ? (11 + j) : (j - 4)) : SPECIAL[c][j];
        const float2 vv = *(const float2*)(kvp +
            ((size_t)((b * 2 + 1) * NSLOT + sj)) * EMB + h * HD + lane * 2);
        accv.x += sc[j] * vv.x;
        accv.y += sc[j] * vv.y;
    }
    accv.x *= inv;
    accv.y *= inv;
    unsigned int packed = (unsigned int)f2bf(accv.x) | ((unsigned int)f2bf(accv.y) << 16);
    *(unsigned int*)(o + ((size_t)(b * SEQ + t)) * EMB + h * HD + lane * 2) = packed;
}

// ---------------- launcher ----------------
extern "C" void kernel_launch(void* const* d_in, const int* in_sizes, int n_in,
                              void* d_out, int out_size, void* d_ws, size_t ws_size,
                              hipStream_t stream) {
    const float* q    = (const float*)d_in[0];
    const float* k    = (const float*)d_in[1];
    const float* v    = (const float*)d_in[2];
    const float* ipw  = (const float*)d_in[3];
    const float* ipb  = (const float*)d_in[4];
    const float* outw = (const float*)d_in[5];
    const float* outb = (const float*)d_in[6];
    float* out = (float*)d_out;

    int Bb = in_sizes[0] / (SEQ * EMB);     // batch (=2)
    int M  = Bb * SEQ;                      // 8192

    // workspace layout (o_bf16 aliases q_bf16: dead after GEMM1, stream-ordered)
    float*    qp   = (float*)d_ws;                          // M x EMB fp32 (32 MB)
    ushort_t* qbf  = (ushort_t*)(qp + (size_t)M * EMB);     // M x EMB bf16 (16 MB), reused as o_bf16
    float*    kvp  = (float*)(qbf + (size_t)M * EMB);       // 60 x EMB fp32
    ushort_t* wqbf = (ushort_t*)(kvp + (size_t)Bb * 2 * NSLOT * EMB);  // EMB x EMB bf16 (2 MB)
    ushort_t* owbf = wqbf + (size_t)EMB * EMB;              // EMB x EMB bf16 (2 MB)

    int nq = M * EMB;        // 8388608
    int nw = EMB * EMB;      // 1048576

    // 1. conversions
    cvt_f32_bf16<<<dim3(nq / (256 * 8)), dim3(256), 0, stream>>>(q, qbf, nq);
    cvt_f32_bf16<<<dim3(nw / (256 * 8)), dim3(256), 0, stream>>>(ipw, wqbf, nw);     // Wq = ipw[:E]
    cvt_f32_bf16<<<dim3(nw / (256 * 8)), dim3(256), 0, stream>>>(outw, owbf, nw);
    // 2. project only the NSLOT needed k/v rows per batch
    proj_kv_small<<<dim3(Bb * 2 * 64), dim3(256), 0, stream>>>(k, v, ipw, ipb, kvp);
    // 3. q projection (bf16 MFMA, global_load_lds staging)
    gemm_bt_bf16<<<dim3((M / BM) * (EMB / BN)), dim3(256), 0, stream>>>(
        qbf, wqbf, ipb, qp, M, EMB, EMB);
    // 4. windowed attention (writes bf16 o over qbf region)
    attn_win<<<dim3(Bb * SEQ * NH / 4), dim3(256), 0, stream>>>(qp, kvp, qbf);
    // 5. output projection
    gemm_bt_bf16<<<dim3((M / BM) * (EMB / BN)), dim3(256), 0, stream>>>(
        qbf, owbf, outb, out, M, EMB, EMB);
}

// Round 4
// 116.541 us; speedup vs baseline: 2.4813x; 1.4038x over previous
//
#include <hip/hip_runtime.h>
#include <hip/hip_bf16.h>
#include <math.h>

// ---------------- problem constants ----------------
#define SEQ   4096
#define EMB   1024
#define NH    8
#define HD    128
#define NSLOT 15   // distinct gathered positions: 0..10, S-4..S-1 (+1 zero pad slot = 16)

typedef __attribute__((ext_vector_type(8))) short bf16x8;
typedef __attribute__((ext_vector_type(4))) float f32x4;
typedef __attribute__((ext_vector_type(8))) unsigned short ushort8v;
typedef unsigned short ushort_t;

// per-t slot multiplicity masks, 2 bits per slot (slot s at bits 2s..2s+1).
// cases 0..6 = boundary t in {0,1,2,3,S-3,S-2,S-1}; case 7 = interior.
// Sum of multiplicities is 8 for every case (the 8 window positions).
__device__ __constant__ unsigned int MULT[8] = {
    0x00005555u,  // t=0:   slots {0..7}
    0x10015055u,  // t=1:   {0,1,2,3,6,7,8,14}
    0x14050055u,  // t=2:   {0,1,2,3,8,9,13,14}
    0x15100055u,  // t=3:   {0,1,2,3,10,12,13,14}
    0x15800015u,  // t=S-3: {0,1,2, 11x2, 12,13,14}
    0x16800005u,  // t=S-2: {0,1, 11x2, 12x2, 13,14}
    0x1A800001u,  // t=S-1: {0, 11x2, 12x2, 13x2, 14}
    0x15400055u   // interior: {0,1,2,3,11,12,13,14}
};

__device__ __forceinline__ unsigned short f2bf(float x) {
    unsigned int u = __float_as_uint(x);
    return (unsigned short)((u + 0x7FFFu + ((u >> 16) & 1u)) >> 16);
}

__device__ __forceinline__ ushort8v pack8(float4 a, float4 b) {
    ushort8v r;
    r[0] = f2bf(a.x); r[1] = f2bf(a.y); r[2] = f2bf(a.z); r[3] = f2bf(a.w);
    r[4] = f2bf(b.x); r[5] = f2bf(b.y); r[6] = f2bf(b.z); r[7] = f2bf(b.w);
    return r;
}

// async global->LDS, 16B per lane; lds ptr must be wave-uniform
__device__ __forceinline__ void gld16(const ushort_t* g, ushort_t* l) {
    __builtin_amdgcn_global_load_lds(
        (const __attribute__((address_space(1))) unsigned int*)g,
        (__attribute__((address_space(3))) unsigned int*)l,
        16, 0, 0);
}

// ---------------- fp32 -> bf16 conversion (memory-bound) ----------------
__global__ __launch_bounds__(256) void cvt_f32_bf16(
    const float* __restrict__ src, ushort_t* __restrict__ dst, int n) {
    int i = (blockIdx.x * 256 + threadIdx.x) * 8;
    if (i < n) {
        float4 a = *(const float4*)&src[i];
        float4 b = *(const float4*)&src[i + 4];
        *(ushort8v*)&dst[i] = pack8(a, b);
    }
}

// ---------------- small k/v projection -> bf16 khb[b][h][16s][128d], vhbT[b][h][128d][16s] ----------------
__global__ __launch_bounds__(256) void proj_kv_small(
    const float* __restrict__ k, const float* __restrict__ v,
    const float* __restrict__ ipw, const float* __restrict__ ipb,
    ushort_t* __restrict__ khb, ushort_t* __restrict__ vhbT) {
    int fc  = blockIdx.x & 63;
    int bkv = blockIdx.x >> 6;
    int kv  = bkv & 1;
    int b   = bkv >> 1;

    const float* x0 = (kv ? v : k) + (size_t)b * SEQ * EMB;
    const float* Wm = ipw + (size_t)(1 + kv) * EMB * EMB;
    const float* bb = ipb + (size_t)(1 + kv) * EMB;

    __shared__ __align__(16) float xs[NSLOT][EMB];
    int tid = threadIdx.x;
#pragma unroll
    for (int i = 0; i < NSLOT; i++) {
        int pos = (i < 11) ? i : (SEQ - 4 + (i - 11));
        *(float4*)&xs[i][tid * 4] = *(const float4*)&x0[(size_t)pos * EMB + tid * 4];
    }
    __syncthreads();

    int row  = tid >> 4;               // slot 0..15 (15 = zero pad)
    int feat = fc * 16 + (tid & 15);
    float val = 0.f;
    if (row < NSLOT) {
        const float* wrow = Wm + (size_t)feat * EMB;
        float acc = 0.f;
        for (int kk = 0; kk < EMB; kk += 4) {
            float4 xv = *(const float4*)&xs[row][kk];
            float4 wv = *(const float4*)&wrow[kk];
            acc += xv.x * wv.x + xv.y * wv.y + xv.z * wv.z + xv.w * wv.w;
        }
        val = acc + bb[feat];
    }
    int h = feat >> 7, d = feat & 127;
    if (kv == 0) khb [((size_t)(b * NH + h) * 16 + row) * HD + d] = f2bf(val);
    else         vhbT[((size_t)(b * NH + h) * HD + d) * 16 + row] = f2bf(val);
}

// ---------------- GEMM tiles ----------------
#define BM 128
#define BN 128
#define BK 32

// plain bf16 MFMA GEMM (m97 structure): C[M,N] = A @ Wt^T + bias, fp32 out
__global__ __launch_bounds__(256) void gemm_bt_bf16(
    const ushort_t* __restrict__ A, const ushort_t* __restrict__ Wt,
    const float* __restrict__ bias, float* __restrict__ C,
    int M, int N, int K) {
    __shared__ __align__(16) ushort_t As[BM * BK];
    __shared__ __align__(16) ushort_t Bs[BN * BK];

    int tid  = threadIdx.x;
    int nbt  = N / BN;
    int mb0  = (blockIdx.x / nbt) * BM;
    int nb0  = (blockIdx.x % nbt) * BN;
    int lane = tid & 63;
    int w    = tid >> 6;
    int wr   = (w >> 1) * 64;
    int wc   = (w & 1) * 64;

    int sr0  = w * 32 + (lane >> 2);
    int kcol = (lane & 3) * 8;
    const ushort_t* asrc0 = A  + (size_t)(mb0 + sr0) * K + kcol;
    const ushort_t* asrc1 = A  + (size_t)(mb0 + sr0 + 16) * K + kcol;
    const ushort_t* bsrc0 = Wt + (size_t)(nb0 + sr0) * K + kcol;
    const ushort_t* bsrc1 = Wt + (size_t)(nb0 + sr0 + 16) * K + kcol;
    ushort_t* adst0 = &As[(w * 2 + 0) * 512];
    ushort_t* adst1 = &As[(w * 2 + 1) * 512];
    ushort_t* bdst0 = &Bs[(w * 2 + 0) * 512];
    ushort_t* bdst1 = &Bs[(w * 2 + 1) * 512];

    f32x4 acc[4][4] = {};
    int kgrp = (lane >> 4) * 8;
    int rA   = wr + (lane & 15);
    int rB   = wc + (lane & 15);

    for (int kb = 0; kb < K; kb += BK) {
        __syncthreads();
        gld16(asrc0 + kb, adst0);
        gld16(asrc1 + kb, adst1);
        gld16(bsrc0 + kb, bdst0);
        gld16(bsrc1 + kb, bdst1);
        __syncthreads();

        bf16x8 afr[4], bfr[4];
#pragma unroll
        for (int m = 0; m < 4; m++)
            afr[m] = *(const bf16x8*)&As[(rA + m * 16) * BK + kgrp];
#pragma unroll
        for (int n = 0; n < 4; n++)
            bfr[n] = *(const bf16x8*)&Bs[(rB + n * 16) * BK + kgrp];
#pragma unroll
        for (int m = 0; m < 4; m++)
#pragma unroll
            for (int n = 0; n < 4; n++)
                acc[m][n] = __builtin_amdgcn_mfma_f32_16x16x32_bf16(
                    afr[m], bfr[n], acc[m][n], 0, 0, 0);
    }

    int rowb = mb0 + wr + ((lane >> 4) * 4);
    int colb = nb0 + wc + (lane & 15);
#pragma unroll
    for (int n = 0; n < 4; n++) {
        int col = colb + n * 16;
        float bn = bias[col];
#pragma unroll
        for (int m = 0; m < 4; m++)
#pragma unroll
            for (int r = 0; r < 4; r++)
                C[(size_t)(rowb + m * 16 + r) * N + col] = acc[m][n][r] + bn;
    }
}

// ---------------- fused q-projection + windowed attention ----------------
// Block = 128 t's x one head. Epilogue: qh->LDS (bf16, T2 swizzle), S=qh@kh^T (MFMA),
// slot-space softmax with multiplicity mask, PV (MFMA, zero-padded K), write o bf16.
__global__ __launch_bounds__(256) void gemm_qattn(
    const ushort_t* __restrict__ A, const ushort_t* __restrict__ Wt,
    const float* __restrict__ bias,
    const ushort_t* __restrict__ khb, const ushort_t* __restrict__ vhbT,
    ushort_t* __restrict__ obf, int M, int N, int K) {
    union SMem {
        struct { ushort_t As[BM * BK]; ushort_t Bs[BN * BK]; } g;  // 16 KB
        struct { ushort_t qs[128 * 128]; ushort_t pl[128 * 20]; } a; // 32+5 KB
    };
    __shared__ __align__(16) SMem sm;

    int tid  = threadIdx.x;
    int nbt  = N / BN;                 // = 8 = heads
    int mb0  = (blockIdx.x / nbt) * BM;
    int nb0  = (blockIdx.x % nbt) * BN;
    int lane = tid & 63;
    int w    = tid >> 6;
    int wr   = (w >> 1) * 64;
    int wc   = (w & 1) * 64;

    int sr0  = w * 32 + (lane >> 2);
    int kcol = (lane & 3) * 8;
    const ushort_t* asrc0 = A  + (size_t)(mb0 + sr0) * K + kcol;
    const ushort_t* asrc1 = A  + (size_t)(mb0 + sr0 + 16) * K + kcol;
    const ushort_t* bsrc0 = Wt + (size_t)(nb0 + sr0) * K + kcol;
    const ushort_t* bsrc1 = Wt + (size_t)(nb0 + sr0 + 16) * K + kcol;
    ushort_t* adst0 = &sm.g.As[(w * 2 + 0) * 512];
    ushort_t* adst1 = &sm.g.As[(w * 2 + 1) * 512];
    ushort_t* bdst0 = &sm.g.Bs[(w * 2 + 0) * 512];
    ushort_t* bdst1 = &sm.g.Bs[(w * 2 + 1) * 512];

    f32x4 acc[4][4] = {};
    int kgrp = (lane >> 4) * 8;
    int rA   = wr + (lane & 15);
    int rB   = wc + (lane & 15);

    for (int kb = 0; kb < K; kb += BK) {
        __syncthreads();
        gld16(asrc0 + kb, adst0);
        gld16(asrc1 + kb, adst1);
        gld16(bsrc0 + kb, bdst0);
        gld16(bsrc1 + kb, bdst1);
        __syncthreads();

        bf16x8 afr[4], bfr[4];
#pragma unroll
        for (int m = 0; m < 4; m++)
            afr[m] = *(const bf16x8*)&sm.g.As[(rA + m * 16) * BK + kgrp];
#pragma unroll
        for (int n = 0; n < 4; n++)
            bfr[n] = *(const bf16x8*)&sm.g.Bs[(rB + n * 16) * BK + kgrp];
#pragma unroll
        for (int m = 0; m < 4; m++)
#pragma unroll
            for (int n = 0; n < 4; n++)
                acc[m][n] = __builtin_amdgcn_mfma_f32_16x16x32_bf16(
                    afr[m], bfr[n], acc[m][n], 0, 0, 0);
    }

    // ---- qh (+bias) -> LDS bf16, XOR-swizzled rows ----
    __syncthreads();   // all waves done reading As/Bs before union reuse
    int rowb_t = wr + ((lane >> 4) * 4);
    int colb_t = wc + (lane & 15);
#pragma unroll
    for (int n = 0; n < 4; n++) {
        int col = colb_t + n * 16;
        float bn = bias[nb0 + col];
#pragma unroll
        for (int m = 0; m < 4; m++)
#pragma unroll
            for (int r = 0; r < 4; r++) {
                int row = rowb_t + m * 16 + r;
                sm.a.qs[row * 128 + (col ^ ((row & 7) << 3))] = f2bf(acc[m][n][r] + bn);
            }
    }
    __syncthreads();

    int bidx = (mb0 >= SEQ) ? 1 : 0;
    int h    = nb0 >> 7;

    // ---- scores + softmax (waves with wc==0 cover all 128 rows) ----
    if (wc == 0) {
        const ushort_t* khB = khb + ((size_t)(bidx * NH + h) * 16 + (lane & 15)) * HD + kgrp;
        bf16x8 khf[4];
#pragma unroll
        for (int kk = 0; kk < 4; kk++) khf[kk] = *(const bf16x8*)(khB + kk * 32);

        int s_slot = lane & 15;
        unsigned int slot2 = (unsigned int)(s_slot * 2);
#pragma unroll
        for (int m = 0; m < 4; m++) {
            int arow = wr + m * 16 + (lane & 15);
            f32x4 s = {};
#pragma unroll
            for (int kk = 0; kk < 4; kk++) {
                int c0 = (kk * 32 + kgrp) ^ ((arow & 7) << 3);
                bf16x8 qf = *(const bf16x8*)&sm.a.qs[arow * 128 + c0];
                s = __builtin_amdgcn_mfma_f32_16x16x32_bf16(qf, khf[kk], s, 0, 0, 0);
            }
            // D layout: row=t=(lane>>4)*4+r (within 16-block), col=slot=lane&15
#pragma unroll
            for (int r = 0; r < 4; r++) {
                int trow = wr + m * 16 + ((lane >> 4) * 4) + r;      // tile-local t
                int tl   = (mb0 + trow) & (SEQ - 1);
                int cse  = (tl >= 4 && tl <= SEQ - 4) ? 7 : ((tl < 4) ? tl : tl - (SEQ - 3) + 4);
                float mult = (float)((MULT[cse] >> slot2) & 3u);
                float vv = s[r] * 0.08838834764831845f;              // 1/sqrt(128)
                float vm = (mult != 0.f) ? vv : -1e30f;
#pragma unroll
                for (int sh = 1; sh < 16; sh <<= 1) vm = fmaxf(vm, __shfl_xor(vm, sh, 64));
                float e = mult * expf(vv - vm);
                float z = e;
#pragma unroll
                for (int sh = 1; sh < 16; sh <<= 1) z += __shfl_xor(z, sh, 64);
                sm.a.pl[trow * 20 + s_slot] = f2bf(e / z);           // stride 20: conflict-free
            }
        }
    }
    __syncthreads();

    // ---- PV: O[t,d] = sum_s P[t,s] * vh[s,d]  (K=16 zero-padded to 32) ----
    const ushort_t* vhB = vhbT + (size_t)(bidx * NH + h) * HD * 16;
    int g4 = lane >> 4;
    bf16x8 vhf[4];
#pragma unroll
    for (int n = 0; n < 4; n++) {
        bf16x8 z8 = {0, 0, 0, 0, 0, 0, 0, 0};
        if (g4 < 2)
            z8 = *(const bf16x8*)(vhB + (size_t)(wc + n * 16 + (lane & 15)) * 16 + g4 * 8);
        vhf[n] = z8;
    }
#pragma unroll
    for (int m = 0; m < 4; m++) {
        bf16x8 paf = {0, 0, 0, 0, 0, 0, 0, 0};
        if (g4 < 2)
            paf = *(const bf16x8*)&sm.a.pl[(wr + m * 16 + (lane & 15)) * 20 + g4 * 8];
#pragma unroll
        for (int n = 0; n < 4; n++) {
            f32x4 pv = {};
            pv = __builtin_amdgcn_mfma_f32_16x16x32_bf16(paf, vhf[n], pv, 0, 0, 0);
            int col = nb0 + wc + n * 16 + (lane & 15);
#pragma unroll
            for (int r = 0; r < 4; r++) {
                int row = mb0 + wr + m * 16 + ((lane >> 4) * 4) + r;
                obf[(size_t)row * EMB + col] = f2bf(pv[r]);
            }
        }
    }
}

// ---------------- launcher ----------------
extern "C" void kernel_launch(void* const* d_in, const int* in_sizes, int n_in,
                              void* d_out, int out_size, void* d_ws, size_t ws_size,
                              hipStream_t stream) {
    const float* q    = (const float*)d_in[0];
    const float* k    = (const float*)d_in[1];
    const float* v    = (const float*)d_in[2];
    const float* ipw  = (const float*)d_in[3];
    const float* ipb  = (const float*)d_in[4];
    const float* outw = (const float*)d_in[5];
    const float* outb = (const float*)d_in[6];
    float* out = (float*)d_out;

    int Bb = in_sizes[0] / (SEQ * EMB);     // batch (=2)
    int M  = Bb * SEQ;                      // 8192

    ushort_t* qbf  = (ushort_t*)d_ws;                  // M x EMB bf16 (16 MB)
    ushort_t* obf  = qbf + (size_t)M * EMB;            // M x EMB bf16 (16 MB)
    ushort_t* wqbf = obf + (size_t)M * EMB;            // EMB x EMB bf16 (2 MB)
    ushort_t* owbf = wqbf + (size_t)EMB * EMB;         // EMB x EMB bf16 (2 MB)
    ushort_t* khb  = owbf + (size_t)EMB * EMB;         // Bb*NH*16*HD bf16 (64 KB)
    ushort_t* vhbT = khb + (size_t)Bb * NH * 16 * HD;  // Bb*NH*HD*16 bf16 (64 KB)

    int nq = M * EMB;
    int nw = EMB * EMB;

    cvt_f32_bf16<<<dim3(nq / (256 * 8)), dim3(256), 0, stream>>>(q, qbf, nq);
    cvt_f32_bf16<<<dim3(nw / (256 * 8)), dim3(256), 0, stream>>>(ipw, wqbf, nw);   // Wq
    cvt_f32_bf16<<<dim3(nw / (256 * 8)), dim3(256), 0, stream>>>(outw, owbf, nw);
    proj_kv_small<<<dim3(Bb * 2 * 64), dim3(256), 0, stream>>>(k, v, ipw, ipb, khb, vhbT);
    gemm_qattn<<<dim3((M / BM) * (EMB / BN)), dim3(256), 0, stream>>>(
        qbf, wqbf, ipb, khb, vhbT, obf, M, EMB, EMB);
    gemm_bt_bf16<<<dim3((M / BM) * (EMB / BN)), dim3(256), 0, stream>>>(
        obf, owbf, outb, out, M, EMB, EMB);
}

// Round 5
// 105.597 us; speedup vs baseline: 2.7384x; 1.1036x over previous
//
#include <hip/hip_runtime.h>
#include <hip/hip_bf16.h>
#include <math.h>

// ---------------- problem constants ----------------
#define SEQ   4096
#define EMB   1024
#define NH    8
#define HD    128
#define NSLOT 15   // distinct gathered positions: 0..10, S-4..S-1 (+1 zero pad slot = 16)

typedef __attribute__((ext_vector_type(8))) short bf16x8;
typedef __attribute__((ext_vector_type(4))) float f32x4;
typedef __attribute__((ext_vector_type(8))) unsigned short ushort8v;
typedef unsigned short ushort_t;

// per-t slot multiplicity masks, 2 bits per slot (slot s at bits 2s..2s+1).
__device__ __constant__ unsigned int MULT[8] = {
    0x00005555u,  // t=0:   slots {0..7}
    0x10015055u,  // t=1:   {0,1,2,3,6,7,8,14}
    0x14050055u,  // t=2:   {0,1,2,3,8,9,13,14}
    0x15100055u,  // t=3:   {0,1,2,3,10,12,13,14}
    0x15800015u,  // t=S-3: {0,1,2, 11x2, 12,13,14}
    0x16800005u,  // t=S-2: {0,1, 11x2, 12x2, 13,14}
    0x1A800001u,  // t=S-1: {0, 11x2, 12x2, 13x2, 14}
    0x15400055u   // interior: {0,1,2,3,11,12,13,14}
};

__device__ __forceinline__ unsigned short f2bf(float x) {
    unsigned int u = __float_as_uint(x);
    return (unsigned short)((u + 0x7FFFu + ((u >> 16) & 1u)) >> 16);
}

__device__ __forceinline__ ushort8v pack8(float4 a, float4 b) {
    ushort8v r;
    r[0] = f2bf(a.x); r[1] = f2bf(a.y); r[2] = f2bf(a.z); r[3] = f2bf(a.w);
    r[4] = f2bf(b.x); r[5] = f2bf(b.y); r[6] = f2bf(b.z); r[7] = f2bf(b.w);
    return r;
}

// async global->LDS, 16B per lane; lds ptr must be wave-uniform
__device__ __forceinline__ void gld16(const ushort_t* g, ushort_t* l) {
    __builtin_amdgcn_global_load_lds(
        (const __attribute__((address_space(1))) unsigned int*)g,
        (__attribute__((address_space(3))) unsigned int*)l,
        16, 0, 0);
}

// ---------------- fp32 -> bf16 conversion (memory-bound) ----------------
__global__ __launch_bounds__(256) void cvt_f32_bf16(
    const float* __restrict__ src, ushort_t* __restrict__ dst, int n) {
    int i = (blockIdx.x * 256 + threadIdx.x) * 8;
    if (i < n) {
        float4 a = *(const float4*)&src[i];
        float4 b = *(const float4*)&src[i + 4];
        *(ushort8v*)&dst[i] = pack8(a, b);
    }
}

// ---------------- small k/v projection -> bf16 khb[b][h][16s][128d], vhbT[b][h][128d][16s] ----------------
__global__ __launch_bounds__(256) void proj_kv_small(
    const float* __restrict__ k, const float* __restrict__ v,
    const float* __restrict__ ipw, const float* __restrict__ ipb,
    ushort_t* __restrict__ khb, ushort_t* __restrict__ vhbT) {
    int fc  = blockIdx.x & 63;
    int bkv = blockIdx.x >> 6;
    int kv  = bkv & 1;
    int b   = bkv >> 1;

    const float* x0 = (kv ? v : k) + (size_t)b * SEQ * EMB;
    const float* Wm = ipw + (size_t)(1 + kv) * EMB * EMB;
    const float* bb = ipb + (size_t)(1 + kv) * EMB;

    __shared__ __align__(16) float xs[NSLOT][EMB];
    int tid = threadIdx.x;
#pragma unroll
    for (int i = 0; i < NSLOT; i++) {
        int pos = (i < 11) ? i : (SEQ - 4 + (i - 11));
        *(float4*)&xs[i][tid * 4] = *(const float4*)&x0[(size_t)pos * EMB + tid * 4];
    }
    __syncthreads();

    int row  = tid >> 4;               // slot 0..15 (15 = zero pad)
    int feat = fc * 16 + (tid & 15);
    float val = 0.f;
    if (row < NSLOT) {
        const float* wrow = Wm + (size_t)feat * EMB;
        float acc = 0.f;
        for (int kk = 0; kk < EMB; kk += 4) {
            float4 xv = *(const float4*)&xs[row][kk];
            float4 wv = *(const float4*)&wrow[kk];
            acc += xv.x * wv.x + xv.y * wv.y + xv.z * wv.z + xv.w * wv.w;
        }
        val = acc + bb[feat];
    }
    int h = feat >> 7, d = feat & 127;
    if (kv == 0) khb [((size_t)(b * NH + h) * 16 + row) * HD + d] = f2bf(val);
    else         vhbT[((size_t)(b * NH + h) * HD + d) * 16 + row] = f2bf(val);
}

// ---------------- GEMM tiles ----------------
#define BM 128
#define BN 128
#define BK 32

// bijective chunked XCD swizzle (nwg % 8 == 0): same-A-tile blocks -> same XCD
__device__ __forceinline__ int xcd_swz(int bid, int nwg) {
    int cpx = nwg >> 3;
    return (bid & 7) * cpx + (bid >> 3);
}

// 2-phase double-buffered bf16 MFMA GEMM: C[M,N] = A @ Wt^T + bias, fp32 out
__global__ __launch_bounds__(256) void gemm_bt_bf16(
    const ushort_t* __restrict__ A, const ushort_t* __restrict__ Wt,
    const float* __restrict__ bias, float* __restrict__ C,
    int M, int N, int K) {
    __shared__ __align__(16) ushort_t As[2][BM * BK];   // 2 x 8 KB
    __shared__ __align__(16) ushort_t Bs[2][BN * BK];   // 2 x 8 KB

    int tid  = threadIdx.x;
    int nbt  = N / BN;
    int lb   = xcd_swz(blockIdx.x, gridDim.x);
    int mb0  = (lb / nbt) * BM;
    int nb0  = (lb % nbt) * BN;
    int lane = tid & 63;
    int w    = tid >> 6;
    int wr   = (w >> 1) * 64;
    int wc   = (w & 1) * 64;

    int sr0  = w * 32 + (lane >> 2);
    int kcol = (lane & 3) * 8;
    const ushort_t* asrc0 = A  + (size_t)(mb0 + sr0) * K + kcol;
    const ushort_t* asrc1 = A  + (size_t)(mb0 + sr0 + 16) * K + kcol;
    const ushort_t* bsrc0 = Wt + (size_t)(nb0 + sr0) * K + kcol;
    const ushort_t* bsrc1 = Wt + (size_t)(nb0 + sr0 + 16) * K + kcol;

#define STAGE_G(buf, kb) do {                          \
        ushort_t* ad = &As[(buf)][(w * 2) * 512];      \
        ushort_t* bd = &Bs[(buf)][(w * 2) * 512];      \
        gld16(asrc0 + (kb), ad);                       \
        gld16(asrc1 + (kb), ad + 512);                 \
        gld16(bsrc0 + (kb), bd);                       \
        gld16(bsrc1 + (kb), bd + 512);                 \
    } while (0)

    f32x4 acc[4][4] = {};
    int kgrp = (lane >> 4) * 8;
    int rA   = wr + (lane & 15);
    int rB   = wc + (lane & 15);

    STAGE_G(0, 0);
    __syncthreads();                       // drains vmcnt(0): tile 0 visible

    for (int kb = 0, cur = 0; kb < K; kb += BK, cur ^= 1) {
        if (kb + BK < K) STAGE_G(cur ^ 1, kb + BK);   // prefetch overlaps compute

        bf16x8 afr[4], bfr[4];
#pragma unroll
        for (int m = 0; m < 4; m++)
            afr[m] = *(const bf16x8*)&As[cur][(rA + m * 16) * BK + kgrp];
#pragma unroll
        for (int n = 0; n < 4; n++)
            bfr[n] = *(const bf16x8*)&Bs[cur][(rB + n * 16) * BK + kgrp];
#pragma unroll
        for (int m = 0; m < 4; m++)
#pragma unroll
            for (int n = 0; n < 4; n++)
                acc[m][n] = __builtin_amdgcn_mfma_f32_16x16x32_bf16(
                    afr[m], bfr[n], acc[m][n], 0, 0, 0);

        __syncthreads();                   // one barrier per K-step (drains stage)
    }

    int rowb = mb0 + wr + ((lane >> 4) * 4);
    int colb = nb0 + wc + (lane & 15);
#pragma unroll
    for (int n = 0; n < 4; n++) {
        int col = colb + n * 16;
        float bn = bias[col];
#pragma unroll
        for (int m = 0; m < 4; m++)
#pragma unroll
            for (int r = 0; r < 4; r++)
                C[(size_t)(rowb + m * 16 + r) * N + col] = acc[m][n][r] + bn;
    }
#undef STAGE_G
}

// ---------------- fused q-projection + windowed attention (2-phase main loop) ----------------
__global__ __launch_bounds__(256) void gemm_qattn(
    const ushort_t* __restrict__ A, const ushort_t* __restrict__ Wt,
    const float* __restrict__ bias,
    const ushort_t* __restrict__ khb, const ushort_t* __restrict__ vhbT,
    ushort_t* __restrict__ obf, int M, int N, int K) {
    union SMem {
        struct { ushort_t As[2][BM * BK]; ushort_t Bs[2][BN * BK]; } g;  // 32 KB
        struct { ushort_t qs[128 * 128]; ushort_t pl[128 * 20]; } a;     // 37 KB
    };
    __shared__ __align__(16) SMem sm;

    int tid  = threadIdx.x;
    int nbt  = N / BN;                 // = 8 = heads
    int lb   = xcd_swz(blockIdx.x, gridDim.x);
    int mb0  = (lb / nbt) * BM;
    int nb0  = (lb % nbt) * BN;
    int lane = tid & 63;
    int w    = tid >> 6;
    int wr   = (w >> 1) * 64;
    int wc   = (w & 1) * 64;

    int sr0  = w * 32 + (lane >> 2);
    int kcol = (lane & 3) * 8;
    const ushort_t* asrc0 = A  + (size_t)(mb0 + sr0) * K + kcol;
    const ushort_t* asrc1 = A  + (size_t)(mb0 + sr0 + 16) * K + kcol;
    const ushort_t* bsrc0 = Wt + (size_t)(nb0 + sr0) * K + kcol;
    const ushort_t* bsrc1 = Wt + (size_t)(nb0 + sr0 + 16) * K + kcol;

#define STAGE_Q(buf, kb) do {                            \
        ushort_t* ad = &sm.g.As[(buf)][(w * 2) * 512];   \
        ushort_t* bd = &sm.g.Bs[(buf)][(w * 2) * 512];   \
        gld16(asrc0 + (kb), ad);                         \
        gld16(asrc1 + (kb), ad + 512);                   \
        gld16(bsrc0 + (kb), bd);                         \
        gld16(bsrc1 + (kb), bd + 512);                   \
    } while (0)

    f32x4 acc[4][4] = {};
    int kgrp = (lane >> 4) * 8;
    int rA   = wr + (lane & 15);
    int rB   = wc + (lane & 15);

    STAGE_Q(0, 0);
    __syncthreads();

    for (int kb = 0, cur = 0; kb < K; kb += BK, cur ^= 1) {
        if (kb + BK < K) STAGE_Q(cur ^ 1, kb + BK);

        bf16x8 afr[4], bfr[4];
#pragma unroll
        for (int m = 0; m < 4; m++)
            afr[m] = *(const bf16x8*)&sm.g.As[cur][(rA + m * 16) * BK + kgrp];
#pragma unroll
        for (int n = 0; n < 4; n++)
            bfr[n] = *(const bf16x8*)&sm.g.Bs[cur][(rB + n * 16) * BK + kgrp];
#pragma unroll
        for (int m = 0; m < 4; m++)
#pragma unroll
            for (int n = 0; n < 4; n++)
                acc[m][n] = __builtin_amdgcn_mfma_f32_16x16x32_bf16(
                    afr[m], bfr[n], acc[m][n], 0, 0, 0);

        __syncthreads();
    }
#undef STAGE_Q

    // ---- qh (+bias) -> LDS bf16, XOR-swizzled rows ----
    int rowb_t = wr + ((lane >> 4) * 4);
    int colb_t = wc + (lane & 15);
#pragma unroll
    for (int n = 0; n < 4; n++) {
        int col = colb_t + n * 16;
        float bn = bias[nb0 + col];
#pragma unroll
        for (int m = 0; m < 4; m++)
#pragma unroll
            for (int r = 0; r < 4; r++) {
                int row = rowb_t + m * 16 + r;
                sm.a.qs[row * 128 + (col ^ ((row & 7) << 3))] = f2bf(acc[m][n][r] + bn);
            }
    }
    __syncthreads();

    int bidx = (mb0 >= SEQ) ? 1 : 0;
    int h    = nb0 >> 7;

    // ---- scores + softmax (waves with wc==0 cover all 128 rows) ----
    if (wc == 0) {
        const ushort_t* khB = khb + ((size_t)(bidx * NH + h) * 16 + (lane & 15)) * HD + kgrp;
        bf16x8 khf[4];
#pragma unroll
        for (int kk = 0; kk < 4; kk++) khf[kk] = *(const bf16x8*)(khB + kk * 32);

        int s_slot = lane & 15;
        unsigned int slot2 = (unsigned int)(s_slot * 2);
#pragma unroll
        for (int m = 0; m < 4; m++) {
            int arow = wr + m * 16 + (lane & 15);
            f32x4 s = {};
#pragma unroll
            for (int kk = 0; kk < 4; kk++) {
                int c0 = (kk * 32 + kgrp) ^ ((arow & 7) << 3);
                bf16x8 qf = *(const bf16x8*)&sm.a.qs[arow * 128 + c0];
                s = __builtin_amdgcn_mfma_f32_16x16x32_bf16(qf, khf[kk], s, 0, 0, 0);
            }
#pragma unroll
            for (int r = 0; r < 4; r++) {
                int trow = wr + m * 16 + ((lane >> 4) * 4) + r;
                int tl   = (mb0 + trow) & (SEQ - 1);
                int cse  = (tl >= 4 && tl <= SEQ - 4) ? 7 : ((tl < 4) ? tl : tl - (SEQ - 3) + 4);
                float mult = (float)((MULT[cse] >> slot2) & 3u);
                float vv = s[r] * 0.08838834764831845f;     // 1/sqrt(128)
                float vm = (mult != 0.f) ? vv : -1e30f;
#pragma unroll
                for (int sh = 1; sh < 16; sh <<= 1) vm = fmaxf(vm, __shfl_xor(vm, sh, 64));
                float e = mult * expf(vv - vm);
                float z = e;
#pragma unroll
                for (int sh = 1; sh < 16; sh <<= 1) z += __shfl_xor(z, sh, 64);
                sm.a.pl[trow * 20 + s_slot] = f2bf(e / z);
            }
        }
    }
    __syncthreads();

    // ---- PV: O[t,d] = sum_s P[t,s] * vh[s,d]  (K=16 zero-padded to 32) ----
    const ushort_t* vhB = vhbT + (size_t)(bidx * NH + h) * HD * 16;
    int g4 = lane >> 4;
    bf16x8 vhf[4];
#pragma unroll
    for (int n = 0; n < 4; n++) {
        bf16x8 z8 = {0, 0, 0, 0, 0, 0, 0, 0};
        if (g4 < 2)
            z8 = *(const bf16x8*)(vhB + (size_t)(wc + n * 16 + (lane & 15)) * 16 + g4 * 8);
        vhf[n] = z8;
    }
#pragma unroll
    for (int m = 0; m < 4; m++) {
        bf16x8 paf = {0, 0, 0, 0, 0, 0, 0, 0};
        if (g4 < 2)
            paf = *(const bf16x8*)&sm.a.pl[(wr + m * 16 + (lane & 15)) * 20 + g4 * 8];
#pragma unroll
        for (int n = 0; n < 4; n++) {
            f32x4 pv = {};
            pv = __builtin_amdgcn_mfma_f32_16x16x32_bf16(paf, vhf[n], pv, 0, 0, 0);
            int col = nb0 + wc + n * 16 + (lane & 15);
#pragma unroll
            for (int r = 0; r < 4; r++) {
                int row = mb0 + wr + m * 16 + ((lane >> 4) * 4) + r;
                obf[(size_t)row * EMB + col] = f2bf(pv[r]);
            }
        }
    }
}

// ---------------- launcher ----------------
extern "C" void kernel_launch(void* const* d_in, const int* in_sizes, int n_in,
                              void* d_out, int out_size, void* d_ws, size_t ws_size,
                              hipStream_t stream) {
    const float* q    = (const float*)d_in[0];
    const float* k    = (const float*)d_in[1];
    const float* v    = (const float*)d_in[2];
    const float* ipw  = (const float*)d_in[3];
    const float* ipb  = (const float*)d_in[4];
    const float* outw = (const float*)d_in[5];
    const float* outb = (const float*)d_in[6];
    float* out = (float*)d_out;

    int Bb = in_sizes[0] / (SEQ * EMB);     // batch (=2)
    int M  = Bb * SEQ;                      // 8192

    ushort_t* qbf  = (ushort_t*)d_ws;                  // M x EMB bf16 (16 MB)
    ushort_t* obf  = qbf + (size_t)M * EMB;            // M x EMB bf16 (16 MB)
    ushort_t* wqbf = obf + (size_t)M * EMB;            // EMB x EMB bf16 (2 MB)
    ushort_t* owbf = wqbf + (size_t)EMB * EMB;         // EMB x EMB bf16 (2 MB)
    ushort_t* khb  = owbf + (size_t)EMB * EMB;         // Bb*NH*16*HD bf16 (64 KB)
    ushort_t* vhbT = khb + (size_t)Bb * NH * 16 * HD;  // Bb*NH*HD*16 bf16 (64 KB)

    int nq = M * EMB;
    int nw = EMB * EMB;

    cvt_f32_bf16<<<dim3(nq / (256 * 8)), dim3(256), 0, stream>>>(q, qbf, nq);
    cvt_f32_bf16<<<dim3(nw / (256 * 8)), dim3(256), 0, stream>>>(ipw, wqbf, nw);   // Wq
    cvt_f32_bf16<<<dim3(nw / (256 * 8)), dim3(256), 0, stream>>>(outw, owbf, nw);
    proj_kv_small<<<dim3(Bb * 2 * 64), dim3(256), 0, stream>>>(k, v, ipw, ipb, khb, vhbT);
    gemm_qattn<<<dim3((M / BM) * (EMB / BN)), dim3(256), 0, stream>>>(
        qbf, wqbf, ipb, khb, vhbT, obf, M, EMB, EMB);
    gemm_bt_bf16<<<dim3((M / BM) * (EMB / BN)), dim3(256), 0, stream>>>(
        obf, owbf, outb, out, M, EMB, EMB);
}

// Round 6
// 104.770 us; speedup vs baseline: 2.7600x; 1.0079x over previous
//
#include <hip/hip_runtime.h>
#include <hip/hip_bf16.h>
#include <math.h>

// ---------------- problem constants ----------------
#define SEQ   4096
#define EMB   1024
#define NH    8
#define HD    128
#define NSLOT 15   // distinct gathered positions: 0..10, S-4..S-1 (+1 zero pad slot = 16)

typedef __attribute__((ext_vector_type(8))) short bf16x8;
typedef __attribute__((ext_vector_type(4))) float f32x4;
typedef __attribute__((ext_vector_type(8))) unsigned short ushort8v;
typedef unsigned short ushort_t;

// per-t slot multiplicity masks, 2 bits per slot (slot s at bits 2s..2s+1).
__device__ __constant__ unsigned int MULT[8] = {
    0x00005555u,  // t=0:   slots {0..7}
    0x10015055u,  // t=1:   {0,1,2,3,6,7,8,14}
    0x14050055u,  // t=2:   {0,1,2,3,8,9,13,14}
    0x15100055u,  // t=3:   {0,1,2,3,10,12,13,14}
    0x15800015u,  // t=S-3: {0,1,2, 11x2, 12,13,14}
    0x16800005u,  // t=S-2: {0,1, 11x2, 12x2, 13,14}
    0x1A800001u,  // t=S-1: {0, 11x2, 12x2, 13x2, 14}
    0x15400055u   // interior: {0,1,2,3,11,12,13,14}
};

__device__ __forceinline__ unsigned short f2bf(float x) {
    unsigned int u = __float_as_uint(x);
    return (unsigned short)((u + 0x7FFFu + ((u >> 16) & 1u)) >> 16);
}

__device__ __forceinline__ ushort8v pack8(float4 a, float4 b) {
    ushort8v r;
    r[0] = f2bf(a.x); r[1] = f2bf(a.y); r[2] = f2bf(a.z); r[3] = f2bf(a.w);
    r[4] = f2bf(b.x); r[5] = f2bf(b.y); r[6] = f2bf(b.z); r[7] = f2bf(b.w);
    return r;
}

// async global->LDS, 16B per lane; lds ptr must be wave-uniform
__device__ __forceinline__ void gld16(const ushort_t* g, ushort_t* l) {
    __builtin_amdgcn_global_load_lds(
        (const __attribute__((address_space(1))) unsigned int*)g,
        (__attribute__((address_space(3))) unsigned int*)l,
        16, 0, 0);
}

// ---------------- fp32 -> bf16 conversion (memory-bound) ----------------
__global__ __launch_bounds__(256) void cvt_f32_bf16(
    const float* __restrict__ src, ushort_t* __restrict__ dst, int n) {
    int i = (blockIdx.x * 256 + threadIdx.x) * 8;
    if (i < n) {
        float4 a = *(const float4*)&src[i];
        float4 b = *(const float4*)&src[i + 4];
        *(ushort8v*)&dst[i] = pack8(a, b);
    }
}

// ---------------- small k/v projection -> bf16 khb[b][h][16s][128d], vhbT[b][h][128d][16s] ----------------
__global__ __launch_bounds__(256) void proj_kv_small(
    const float* __restrict__ k, const float* __restrict__ v,
    const float* __restrict__ ipw, const float* __restrict__ ipb,
    ushort_t* __restrict__ khb, ushort_t* __restrict__ vhbT) {
    int fc  = blockIdx.x & 63;
    int bkv = blockIdx.x >> 6;
    int kv  = bkv & 1;
    int b   = bkv >> 1;

    const float* x0 = (kv ? v : k) + (size_t)b * SEQ * EMB;
    const float* Wm = ipw + (size_t)(1 + kv) * EMB * EMB;
    const float* bb = ipb + (size_t)(1 + kv) * EMB;

    __shared__ __align__(16) float xs[NSLOT][EMB];
    int tid = threadIdx.x;
#pragma unroll
    for (int i = 0; i < NSLOT; i++) {
        int pos = (i < 11) ? i : (SEQ - 4 + (i - 11));
        *(float4*)&xs[i][tid * 4] = *(const float4*)&x0[(size_t)pos * EMB + tid * 4];
    }
    __syncthreads();

    int row  = tid >> 4;               // slot 0..15 (15 = zero pad)
    int feat = fc * 16 + (tid & 15);
    float val = 0.f;
    if (row < NSLOT) {
        const float* wrow = Wm + (size_t)feat * EMB;
        float acc = 0.f;
        for (int kk = 0; kk < EMB; kk += 4) {
            float4 xv = *(const float4*)&xs[row][kk];
            float4 wv = *(const float4*)&wrow[kk];
            acc += xv.x * wv.x + xv.y * wv.y + xv.z * wv.z + xv.w * wv.w;
        }
        val = acc + bb[feat];
    }
    int h = feat >> 7, d = feat & 127;
    if (kv == 0) khb [((size_t)(b * NH + h) * 16 + row) * HD + d] = f2bf(val);
    else         vhbT[((size_t)(b * NH + h) * HD + d) * 16 + row] = f2bf(val);
}

// ---------------- deep-pipelined GEMM geometry ----------------
#define BM 256
#define BN 128
#define BK 64
// per K-tile: A 256x64x2B = 32KB = 32 wave-issues (4/wave); B 128x64x2B = 16 (2/wave)
// 3 LDS buffers, depth-2 prefetch, steady-state vmcnt(6) (= issues of 1 in-flight tile)

// bijective chunked XCD swizzle (nwg % 8 == 0): same-A-panel blocks -> same XCD
__device__ __forceinline__ int xcd_swz(int bid, int nwg) {
    int cpx = nwg >> 3;
    return (bid & 7) * cpx + (bid >> 3);
}

// staging: lane l covers row r0+(l>>3), pre-swizzled global chunk ((l&7)^(l>>3))*8 shorts.
// LDS phys layout: [row][chunk ^ (row&7)] in 8-short granules -> conflict-free b128 reads.
#define STAGE(sA_, sB_, kb_) do {                                            \
        _Pragma("unroll")                                                    \
        for (int i_ = 0; i_ < 4; i_++)                                       \
            gld16(aBase + (size_t)(w * 32 + i_ * 8) * K + (kb_),             \
                  &(sA_)[(w * 32 + i_ * 8) * BK]);                           \
        _Pragma("unroll")                                                    \
        for (int j_ = 0; j_ < 2; j_++)                                       \
            gld16(bBase + (size_t)(w * 16 + j_ * 8) * K + (kb_),             \
                  &(sB_)[(w * 16 + j_ * 8) * BK]);                           \
    } while (0)

#define COMPUTE(sA_, sB_) do {                                               \
        __builtin_amdgcn_s_setprio(1);                                       \
        _Pragma("unroll")                                                    \
        for (int kk_ = 0; kk_ < 2; kk_++) {                                  \
            int col_ = (kk_ * 32 + g * 8) ^ ((fr & 7) << 3);                 \
            bf16x8 afr[4], bfr[4];                                           \
            _Pragma("unroll")                                                \
            for (int m_ = 0; m_ < 4; m_++)                                   \
                afr[m_] = *(const bf16x8*)&(sA_)[(wr + m_ * 16 + fr) * BK + col_]; \
            _Pragma("unroll")                                                \
            for (int n_ = 0; n_ < 4; n_++)                                   \
                bfr[n_] = *(const bf16x8*)&(sB_)[(wc + n_ * 16 + fr) * BK + col_]; \
            _Pragma("unroll")                                                \
            for (int m_ = 0; m_ < 4; m_++)                                   \
                _Pragma("unroll")                                            \
                for (int n_ = 0; n_ < 4; n_++)                               \
                    acc[m_][n_] = __builtin_amdgcn_mfma_f32_16x16x32_bf16(   \
                        afr[m_], bfr[n_], acc[m_][n_], 0, 0, 0);             \
        }                                                                    \
        __builtin_amdgcn_s_setprio(0);                                       \
    } while (0)

// main loop shared by both kernels: counted-vmcnt, one raw barrier per K-step
#define KLOOP(A3_, B3_) do {                                                 \
        STAGE(A3_[0], B3_[0], 0);                                            \
        STAGE(A3_[1], B3_[1], BK);                                           \
        asm volatile("s_waitcnt vmcnt(6)" ::: "memory");                     \
        __builtin_amdgcn_s_barrier();                                        \
        for (int t = 0; t < NT; t++) {                                       \
            int cur = t % 3;                                                 \
            if (t + 2 < NT) {                                                \
                int nxt = (t + 2) % 3;                                       \
                STAGE(A3_[nxt], B3_[nxt], (t + 2) * BK);                     \
            }                                                                \
            COMPUTE(A3_[cur], B3_[cur]);                                     \
            if (t + 2 < NT)                                                  \
                asm volatile("s_waitcnt vmcnt(6)" ::: "memory");             \
            else if (t + 1 < NT)                                             \
                asm volatile("s_waitcnt vmcnt(0)" ::: "memory");             \
            if (t + 1 < NT) __builtin_amdgcn_s_barrier();                    \
        }                                                                    \
    } while (0)

// ---------------- plain GEMM: C[M,N] = A @ Wt^T + bias (fp32 out) ----------------
__global__ __launch_bounds__(512) void gemm_bt_bf16(
    const ushort_t* __restrict__ A, const ushort_t* __restrict__ Wt,
    const float* __restrict__ bias, float* __restrict__ C,
    int M, int N, int K) {
    __shared__ __align__(16) ushort_t sA[3][BM * BK];   // 96 KB
    __shared__ __align__(16) ushort_t sB[3][BN * BK];   // 48 KB

    int tid  = threadIdx.x;
    int nbt  = N / BN;
    int lb   = xcd_swz(blockIdx.x, gridDim.x);
    int mb0  = (lb / nbt) * BM;
    int nb0  = (lb % nbt) * BN;
    int lane = tid & 63;
    int w    = tid >> 6;           // 0..7
    int wr   = (w >> 1) * 64;      // 4x2 wave grid
    int wc   = (w & 1) * 64;
    int fr   = lane & 15;
    int g    = lane >> 4;
    int NT   = K / BK;

    const ushort_t* aBase = A  + (size_t)(mb0 + (lane >> 3)) * K + (((lane & 7) ^ (lane >> 3)) * 8);
    const ushort_t* bBase = Wt + (size_t)(nb0 + (lane >> 3)) * K + (((lane & 7) ^ (lane >> 3)) * 8);

    f32x4 acc[4][4] = {};
    KLOOP(sA, sB);

    // epilogue: C/D layout col=lane&15, row=(lane>>4)*4+reg  [verified m89/m91]
    int rowb = mb0 + wr + g * 4;
    int colb = nb0 + wc + fr;
#pragma unroll
    for (int n = 0; n < 4; n++) {
        int col = colb + n * 16;
        float bn = bias[col];
#pragma unroll
        for (int m = 0; m < 4; m++)
#pragma unroll
            for (int r = 0; r < 4; r++)
                C[(size_t)(rowb + m * 16 + r) * N + col] = acc[m][n][r] + bn;
    }
}

// ---------------- fused q-projection + windowed attention ----------------
// Block = 256 t's x one head (BN=128=HD). Same deep-pipelined main loop, then
// qh->LDS (bf16, swizzled), S=qh@kh^T (MFMA), slot softmax, PV (MFMA), o bf16.
__global__ __launch_bounds__(512) void gemm_qattn(
    const ushort_t* __restrict__ A, const ushort_t* __restrict__ Wt,
    const float* __restrict__ bias,
    const ushort_t* __restrict__ khb, const ushort_t* __restrict__ vhbT,
    ushort_t* __restrict__ obf, int M, int N, int K) {
    union SMem {
        struct { ushort_t A3[3][BM * BK]; ushort_t B3[3][BN * BK]; } gm;  // 144 KB
        struct { ushort_t qs[BM * 128]; ushort_t pl[BM * 20]; } at;       // 74 KB
    };
    __shared__ __align__(16) SMem sm;

    int tid  = threadIdx.x;
    int nbt  = N / BN;                 // = 8 = heads
    int lb   = xcd_swz(blockIdx.x, gridDim.x);
    int mb0  = (lb / nbt) * BM;
    int nb0  = (lb % nbt) * BN;
    int lane = tid & 63;
    int w    = tid >> 6;
    int wr   = (w >> 1) * 64;
    int wc   = (w & 1) * 64;
    int fr   = lane & 15;
    int g    = lane >> 4;
    int NT   = K / BK;

    const ushort_t* aBase = A  + (size_t)(mb0 + (lane >> 3)) * K + (((lane & 7) ^ (lane >> 3)) * 8);
    const ushort_t* bBase = Wt + (size_t)(nb0 + (lane >> 3)) * K + (((lane & 7) ^ (lane >> 3)) * 8);

    f32x4 acc[4][4] = {};
    KLOOP(sm.gm.A3, sm.gm.B3);

    // ---- qh (+bias) -> LDS bf16, XOR-swizzled rows (16B granule) ----
    __syncthreads();   // full drain; all waves done with gm before union reuse
    int rowb_t = wr + g * 4;
    int colb_t = wc + fr;
#pragma unroll
    for (int n = 0; n < 4; n++) {
        int col = colb_t + n * 16;
        float bn = bias[nb0 + col];
#pragma unroll
        for (int m = 0; m < 4; m++)
#pragma unroll
            for (int r = 0; r < 4; r++) {
                int row = rowb_t + m * 16 + r;
                sm.at.qs[row * 128 + (col ^ ((row & 7) << 3))] = f2bf(acc[m][n][r] + bn);
            }
    }
    __syncthreads();

    int bidx = (mb0 >= SEQ) ? 1 : 0;
    int h    = nb0 >> 7;
    int kgrp = g * 8;

    // ---- scores + softmax (the 4 waves with wc==0 cover all 256 rows) ----
    if (wc == 0) {
        const ushort_t* khB = khb + ((size_t)(bidx * NH + h) * 16 + fr) * HD + kgrp;
        bf16x8 khf[4];
#pragma unroll
        for (int kk = 0; kk < 4; kk++) khf[kk] = *(const bf16x8*)(khB + kk * 32);

        unsigned int slot2 = (unsigned int)(fr * 2);
#pragma unroll
        for (int m = 0; m < 4; m++) {
            int arow = wr + m * 16 + fr;
            f32x4 s = {};
#pragma unroll
            for (int kk = 0; kk < 4; kk++) {
                int c0 = (kk * 32 + kgrp) ^ ((arow & 7) << 3);
                bf16x8 qf = *(const bf16x8*)&sm.at.qs[arow * 128 + c0];
                s = __builtin_amdgcn_mfma_f32_16x16x32_bf16(qf, khf[kk], s, 0, 0, 0);
            }
#pragma unroll
            for (int r = 0; r < 4; r++) {
                int trow = wr + m * 16 + g * 4 + r;
                int tl   = (mb0 + trow) & (SEQ - 1);
                int cse  = (tl >= 4 && tl <= SEQ - 4) ? 7 : ((tl < 4) ? tl : tl - (SEQ - 3) + 4);
                float mult = (float)((MULT[cse] >> slot2) & 3u);
                float vv = s[r] * 0.08838834764831845f;     // 1/sqrt(128)
                float vm = (mult != 0.f) ? vv : -1e30f;
#pragma unroll
                for (int sh = 1; sh < 16; sh <<= 1) vm = fmaxf(vm, __shfl_xor(vm, sh, 64));
                float e = mult * expf(vv - vm);
                float z = e;
#pragma unroll
                for (int sh = 1; sh < 16; sh <<= 1) z += __shfl_xor(z, sh, 64);
                sm.at.pl[trow * 20 + fr] = f2bf(e / z);
            }
        }
    }
    __syncthreads();

    // ---- PV: O[t,d] = sum_s P[t,s] * vh[s,d]  (K=16 zero-padded to 32) ----
    const ushort_t* vhB = vhbT + (size_t)(bidx * NH + h) * HD * 16;
    bf16x8 vhf[4];
#pragma unroll
    for (int n = 0; n < 4; n++) {
        bf16x8 z8 = {0, 0, 0, 0, 0, 0, 0, 0};
        if (g < 2)
            z8 = *(const bf16x8*)(vhB + (size_t)(wc + n * 16 + fr) * 16 + g * 8);
        vhf[n] = z8;
    }
#pragma unroll
    for (int m = 0; m < 4; m++) {
        bf16x8 paf = {0, 0, 0, 0, 0, 0, 0, 0};
        if (g < 2)
            paf = *(const bf16x8*)&sm.at.pl[(wr + m * 16 + fr) * 20 + g * 8];
#pragma unroll
        for (int n = 0; n < 4; n++) {
            f32x4 pv = {};
            pv = __builtin_amdgcn_mfma_f32_16x16x32_bf16(paf, vhf[n], pv, 0, 0, 0);
            int col = nb0 + wc + n * 16 + fr;
#pragma unroll
            for (int r = 0; r < 4; r++) {
                int row = mb0 + wr + m * 16 + g * 4 + r;
                obf[(size_t)row * EMB + col] = f2bf(pv[r]);
            }
        }
    }
}

// ---------------- launcher ----------------
extern "C" void kernel_launch(void* const* d_in, const int* in_sizes, int n_in,
                              void* d_out, int out_size, void* d_ws, size_t ws_size,
                              hipStream_t stream) {
    const float* q    = (const float*)d_in[0];
    const float* k    = (const float*)d_in[1];
    const float* v    = (const float*)d_in[2];
    const float* ipw  = (const float*)d_in[3];
    const float* ipb  = (const float*)d_in[4];
    const float* outw = (const float*)d_in[5];
    const float* outb = (const float*)d_in[6];
    float* out = (float*)d_out;

    int Bb = in_sizes[0] / (SEQ * EMB);     // batch (=2)
    int M  = Bb * SEQ;                      // 8192

    ushort_t* qbf  = (ushort_t*)d_ws;                  // M x EMB bf16 (16 MB)
    ushort_t* obf  = qbf + (size_t)M * EMB;            // M x EMB bf16 (16 MB)
    ushort_t* wqbf = obf + (size_t)M * EMB;            // EMB x EMB bf16 (2 MB)
    ushort_t* owbf = wqbf + (size_t)EMB * EMB;         // EMB x EMB bf16 (2 MB)
    ushort_t* khb  = owbf + (size_t)EMB * EMB;         // Bb*NH*16*HD bf16 (64 KB)
    ushort_t* vhbT = khb + (size_t)Bb * NH * 16 * HD;  // Bb*NH*HD*16 bf16 (64 KB)

    int nq = M * EMB;
    int nw = EMB * EMB;

    cvt_f32_bf16<<<dim3(nq / (256 * 8)), dim3(256), 0, stream>>>(q, qbf, nq);
    cvt_f32_bf16<<<dim3(nw / (256 * 8)), dim3(256), 0, stream>>>(ipw, wqbf, nw);   // Wq
    cvt_f32_bf16<<<dim3(nw / (256 * 8)), dim3(256), 0, stream>>>(outw, owbf, nw);
    proj_kv_small<<<dim3(Bb * 2 * 64), dim3(256), 0, stream>>>(k, v, ipw, ipb, khb, vhbT);
    gemm_qattn<<<dim3((M / BM) * (EMB / BN)), dim3(512), 0, stream>>>(
        qbf, wqbf, ipb, khb, vhbT, obf, M, EMB, EMB);
    gemm_bt_bf16<<<dim3((M / BM) * (EMB / BN)), dim3(512), 0, stream>>>(
        obf, owbf, outb, out, M, EMB, EMB);
}

// Round 7
// 102.265 us; speedup vs baseline: 2.8276x; 1.0245x over previous
//
#include <hip/hip_runtime.h>
#include <hip/hip_bf16.h>
#include <math.h>

// ---------------- problem constants ----------------
#define SEQ   4096
#define EMB   1024
#define NH    8
#define HD    128
#define NSLOT 15   // distinct gathered positions: 0..10, S-4..S-1 (+1 zero pad slot = 16)

typedef __attribute__((ext_vector_type(8))) short bf16x8;
typedef __attribute__((ext_vector_type(4))) float f32x4;
typedef __attribute__((ext_vector_type(8))) unsigned short ushort8v;
typedef unsigned short ushort_t;

// per-t slot multiplicity masks, 2 bits per slot (slot s at bits 2s..2s+1).
__device__ __constant__ unsigned int MULT[8] = {
    0x00005555u,  // t=0:   slots {0..7}
    0x10015055u,  // t=1:   {0,1,2,3,6,7,8,14}
    0x14050055u,  // t=2:   {0,1,2,3,8,9,13,14}
    0x15100055u,  // t=3:   {0,1,2,3,10,12,13,14}
    0x15800015u,  // t=S-3: {0,1,2, 11x2, 12,13,14}
    0x16800005u,  // t=S-2: {0,1, 11x2, 12x2, 13,14}
    0x1A800001u,  // t=S-1: {0, 11x2, 12x2, 13x2, 14}
    0x15400055u   // interior: {0,1,2,3,11,12,13,14}
};

__device__ __forceinline__ unsigned short f2bf(float x) {
    unsigned int u = __float_as_uint(x);
    return (unsigned short)((u + 0x7FFFu + ((u >> 16) & 1u)) >> 16);
}

__device__ __forceinline__ ushort8v pack8(float4 a, float4 b) {
    ushort8v r;
    r[0] = f2bf(a.x); r[1] = f2bf(a.y); r[2] = f2bf(a.z); r[3] = f2bf(a.w);
    r[4] = f2bf(b.x); r[5] = f2bf(b.y); r[6] = f2bf(b.z); r[7] = f2bf(b.w);
    return r;
}

// async global->LDS, 16B per lane; lds ptr must be wave-uniform
__device__ __forceinline__ void gld16(const ushort_t* g, ushort_t* l) {
    __builtin_amdgcn_global_load_lds(
        (const __attribute__((address_space(1))) unsigned int*)g,
        (__attribute__((address_space(3))) unsigned int*)l,
        16, 0, 0);
}

// ---------------- fp32 -> bf16 conversion (memory-bound) ----------------
__global__ __launch_bounds__(256) void cvt_f32_bf16(
    const float* __restrict__ src, ushort_t* __restrict__ dst, int n) {
    int i = (blockIdx.x * 256 + threadIdx.x) * 8;
    if (i < n) {
        float4 a = *(const float4*)&src[i];
        float4 b = *(const float4*)&src[i + 4];
        *(ushort8v*)&dst[i] = pack8(a, b);
    }
}

// ---------------- small k/v projection -> bf16 khb[b][h][16s][128d], vhbT[b][h][128d][16s] ----------------
__global__ __launch_bounds__(256) void proj_kv_small(
    const float* __restrict__ k, const float* __restrict__ v,
    const float* __restrict__ ipw, const float* __restrict__ ipb,
    ushort_t* __restrict__ khb, ushort_t* __restrict__ vhbT) {
    int fc  = blockIdx.x & 63;
    int bkv = blockIdx.x >> 6;
    int kv  = bkv & 1;
    int b   = bkv >> 1;

    const float* x0 = (kv ? v : k) + (size_t)b * SEQ * EMB;
    const float* Wm = ipw + (size_t)(1 + kv) * EMB * EMB;
    const float* bb = ipb + (size_t)(1 + kv) * EMB;

    __shared__ __align__(16) float xs[NSLOT][EMB];
    int tid = threadIdx.x;
#pragma unroll
    for (int i = 0; i < NSLOT; i++) {
        int pos = (i < 11) ? i : (SEQ - 4 + (i - 11));
        *(float4*)&xs[i][tid * 4] = *(const float4*)&x0[(size_t)pos * EMB + tid * 4];
    }
    __syncthreads();

    int row  = tid >> 4;               // slot 0..15 (15 = zero pad)
    int feat = fc * 16 + (tid & 15);
    float val = 0.f;
    if (row < NSLOT) {
        const float* wrow = Wm + (size_t)feat * EMB;
        float acc = 0.f;
        for (int kk = 0; kk < EMB; kk += 4) {
            float4 xv = *(const float4*)&xs[row][kk];
            float4 wv = *(const float4*)&wrow[kk];
            acc += xv.x * wv.x + xv.y * wv.y + xv.z * wv.z + xv.w * wv.w;
        }
        val = acc + bb[feat];
    }
    int h = feat >> 7, d = feat & 127;
    if (kv == 0) khb [((size_t)(b * NH + h) * 16 + row) * HD + d] = f2bf(val);
    else         vhbT[((size_t)(b * NH + h) * HD + d) * 16 + row] = f2bf(val);
}

// ---------------- deep-pipelined GEMM geometry ----------------
#define BM 256
#define BN 128
#define BK 64
// 512 threads = 8 waves (4M x 2N), wave output 64x64.
// LDS: 3 buffers (depth-2 prefetch). Stage units per K-tile per wave:
//   U_A = 4 gld16 (A rows w*32..+31), U_B = 2 gld16 (B rows w*16..+15)
// Per K-tile: 2 phases (kk=0/1), each {8 ds_read_b128 | stage unit | barrier |
//   lgkmcnt(0) | setprio 16xMFMA | barrier}; vmcnt(6) once per tile (never 0 mid-loop).

// bijective chunked XCD swizzle (nwg % 8 == 0): same-A-panel blocks -> same XCD
__device__ __forceinline__ int xcd_swz(int bid, int nwg) {
    int cpx = nwg >> 3;
    return (bid & 7) * cpx + (bid >> 3);
}

#define STAGE_A(dst_, kb_) do {                                              \
        _Pragma("unroll")                                                    \
        for (int i_ = 0; i_ < 4; i_++)                                       \
            gld16(aBase + (size_t)(w * 32 + i_ * 8) * K + (kb_),             \
                  &(dst_)[(w * 32 + i_ * 8) * BK]);                          \
    } while (0)

#define STAGE_B(dst_, kb_) do {                                              \
        _Pragma("unroll")                                                    \
        for (int j_ = 0; j_ < 2; j_++)                                       \
            gld16(bBase + (size_t)(w * 16 + j_ * 8) * K + (kb_),             \
                  &(dst_)[(w * 16 + j_ * 8) * BK]);                          \
    } while (0)

#define MFMA16(af_, bf_) do {                                                \
        __builtin_amdgcn_s_setprio(1);                                       \
        _Pragma("unroll")                                                    \
        for (int m_ = 0; m_ < 4; m_++)                                       \
            _Pragma("unroll")                                                \
            for (int n_ = 0; n_ < 4; n_++)                                   \
                acc[m_][n_] = __builtin_amdgcn_mfma_f32_16x16x32_bf16(       \
                    (af_)[m_], (bf_)[n_], acc[m_][n_], 0, 0, 0);             \
        __builtin_amdgcn_s_setprio(0);                                       \
    } while (0)

// fine-grained 2-phase-per-K-tile pipelined loop (template 5, adapted)
#define KLOOP8(A3_, B3_) do {                                                \
        STAGE_A(A3_[0], 0); STAGE_B(B3_[0], 0);                              \
        STAGE_A(A3_[1], BK); STAGE_B(B3_[1], BK);                            \
        asm volatile("s_waitcnt vmcnt(6)" ::: "memory");                     \
        __builtin_amdgcn_s_barrier();                                        \
        for (int t = 0; t < NT; t++) {                                       \
            int cur = t % 3, nxt = (t + 2) % 3;                              \
            bool st = (t + 2 < NT);                                          \
            int kb2 = (t + 2) * BK;                                          \
            const ushort_t* Ac = &A3_[cur][0];                               \
            const ushort_t* Bc = &B3_[cur][0];                               \
            bf16x8 af[4], bf[4];                                             \
            int c0 = (g * 8) ^ frx8;                                         \
            _Pragma("unroll")                                                \
            for (int m_ = 0; m_ < 4; m_++)                                   \
                af[m_] = *(const bf16x8*)&Ac[(wr + m_ * 16 + fr) * BK + c0]; \
            _Pragma("unroll")                                                \
            for (int n_ = 0; n_ < 4; n_++)                                   \
                bf[n_] = *(const bf16x8*)&Bc[(wc + n_ * 16 + fr) * BK + c0]; \
            if (st) STAGE_A(A3_[nxt], kb2);                                  \
            __builtin_amdgcn_s_barrier();                                    \
            asm volatile("s_waitcnt lgkmcnt(0)" ::: "memory");               \
            MFMA16(af, bf);                                                  \
            __builtin_amdgcn_s_barrier();                                    \
            int c1 = (32 + g * 8) ^ frx8;                                    \
            _Pragma("unroll")                                                \
            for (int m_ = 0; m_ < 4; m_++)                                   \
                af[m_] = *(const bf16x8*)&Ac[(wr + m_ * 16 + fr) * BK + c1]; \
            _Pragma("unroll")                                                \
            for (int n_ = 0; n_ < 4; n_++)                                   \
                bf[n_] = *(const bf16x8*)&Bc[(wc + n_ * 16 + fr) * BK + c1]; \
            if (st) STAGE_B(B3_[nxt], kb2);                                  \
            __builtin_amdgcn_s_barrier();                                    \
            asm volatile("s_waitcnt lgkmcnt(0)" ::: "memory");               \
            MFMA16(af, bf);                                                  \
            if (st)                                                          \
                asm volatile("s_waitcnt vmcnt(6)" ::: "memory");             \
            else if (t + 1 < NT)                                             \
                asm volatile("s_waitcnt vmcnt(0)" ::: "memory");             \
            __builtin_amdgcn_s_barrier();                                    \
        }                                                                    \
    } while (0)

// ---------------- plain GEMM: C[M,N] = A @ Wt^T + bias (fp32 out) ----------------
__global__ __launch_bounds__(512) void gemm_bt_bf16(
    const ushort_t* __restrict__ A, const ushort_t* __restrict__ Wt,
    const float* __restrict__ bias, float* __restrict__ C,
    int M, int N, int K) {
    __shared__ __align__(16) ushort_t sA[3][BM * BK];   // 96 KB
    __shared__ __align__(16) ushort_t sB[3][BN * BK];   // 48 KB

    int tid  = threadIdx.x;
    int nbt  = N / BN;
    int lb   = xcd_swz(blockIdx.x, gridDim.x);
    int mb0  = (lb / nbt) * BM;
    int nb0  = (lb % nbt) * BN;
    int lane = tid & 63;
    int w    = tid >> 6;           // 0..7
    int wr   = (w >> 1) * 64;      // 4x2 wave grid
    int wc   = (w & 1) * 64;
    int fr   = lane & 15;
    int g    = lane >> 4;
    int frx8 = (fr & 7) << 3;
    int NT   = K / BK;

    const ushort_t* aBase = A  + (size_t)(mb0 + (lane >> 3)) * K + (((lane & 7) ^ (lane >> 3)) * 8);
    const ushort_t* bBase = Wt + (size_t)(nb0 + (lane >> 3)) * K + (((lane & 7) ^ (lane >> 3)) * 8);

    f32x4 acc[4][4] = {};
    KLOOP8(sA, sB);

    // epilogue: C/D layout col=lane&15, row=(lane>>4)*4+reg  [verified m89/m91]
    int rowb = mb0 + wr + g * 4;
    int colb = nb0 + wc + fr;
#pragma unroll
    for (int n = 0; n < 4; n++) {
        int col = colb + n * 16;
        float bn = bias[col];
#pragma unroll
        for (int m = 0; m < 4; m++)
#pragma unroll
            for (int r = 0; r < 4; r++)
                C[(size_t)(rowb + m * 16 + r) * N + col] = acc[m][n][r] + bn;
    }
}

// ---------------- fused q-projection + windowed attention ----------------
// Block = 256 t's x one head (BN=128=HD). Same pipelined main loop, then
// qh->LDS (bf16, swizzled), S=qh@kh^T (MFMA), slot softmax, PV (MFMA), o bf16.
__global__ __launch_bounds__(512) void gemm_qattn(
    const ushort_t* __restrict__ A, const ushort_t* __restrict__ Wt,
    const float* __restrict__ bias,
    const ushort_t* __restrict__ khb, const ushort_t* __restrict__ vhbT,
    ushort_t* __restrict__ obf, int M, int N, int K) {
    union SMem {
        struct { ushort_t A3[3][BM * BK]; ushort_t B3[3][BN * BK]; } gm;  // 144 KB
        struct { ushort_t qs[BM * 128]; ushort_t pl[BM * 20]; } at;       // 74 KB
    };
    __shared__ __align__(16) SMem sm;

    int tid  = threadIdx.x;
    int nbt  = N / BN;                 // = 8 = heads
    int lb   = xcd_swz(blockIdx.x, gridDim.x);
    int mb0  = (lb / nbt) * BM;
    int nb0  = (lb % nbt) * BN;
    int lane = tid & 63;
    int w    = tid >> 6;
    int wr   = (w >> 1) * 64;
    int wc   = (w & 1) * 64;
    int fr   = lane & 15;
    int g    = lane >> 4;
    int frx8 = (fr & 7) << 3;
    int NT   = K / BK;

    const ushort_t* aBase = A  + (size_t)(mb0 + (lane >> 3)) * K + (((lane & 7) ^ (lane >> 3)) * 8);
    const ushort_t* bBase = Wt + (size_t)(nb0 + (lane >> 3)) * K + (((lane & 7) ^ (lane >> 3)) * 8);

    f32x4 acc[4][4] = {};
    KLOOP8(sm.gm.A3, sm.gm.B3);

    // ---- qh (+bias) -> LDS bf16, XOR-swizzled rows (16B granule) ----
    __syncthreads();   // full drain; all waves done with gm before union reuse
    int rowb_t = wr + g * 4;
    int colb_t = wc + fr;
#pragma unroll
    for (int n = 0; n < 4; n++) {
        int col = colb_t + n * 16;
        float bn = bias[nb0 + col];
#pragma unroll
        for (int m = 0; m < 4; m++)
#pragma unroll
            for (int r = 0; r < 4; r++) {
                int row = rowb_t + m * 16 + r;
                sm.at.qs[row * 128 + (col ^ ((row & 7) << 3))] = f2bf(acc[m][n][r] + bn);
            }
    }
    __syncthreads();

    int bidx = (mb0 >= SEQ) ? 1 : 0;
    int h    = nb0 >> 7;
    int kgrp = g * 8;

    // ---- scores + softmax (the 4 waves with wc==0 cover all 256 rows) ----
    if (wc == 0) {
        const ushort_t* khB = khb + ((size_t)(bidx * NH + h) * 16 + fr) * HD + kgrp;
        bf16x8 khf[4];
#pragma unroll
        for (int kk = 0; kk < 4; kk++) khf[kk] = *(const bf16x8*)(khB + kk * 32);

        unsigned int slot2 = (unsigned int)(fr * 2);
#pragma unroll
        for (int m = 0; m < 4; m++) {
            int arow = wr + m * 16 + fr;
            f32x4 s = {};
#pragma unroll
            for (int kk = 0; kk < 4; kk++) {
                int c0 = (kk * 32 + kgrp) ^ ((arow & 7) << 3);
                bf16x8 qf = *(const bf16x8*)&sm.at.qs[arow * 128 + c0];
                s = __builtin_amdgcn_mfma_f32_16x16x32_bf16(qf, khf[kk], s, 0, 0, 0);
            }
#pragma unroll
            for (int r = 0; r < 4; r++) {
                int trow = wr + m * 16 + g * 4 + r;
                int tl   = (mb0 + trow) & (SEQ - 1);
                int cse  = (tl >= 4 && tl <= SEQ - 4) ? 7 : ((tl < 4) ? tl : tl - (SEQ - 3) + 4);
                float mult = (float)((MULT[cse] >> slot2) & 3u);
                float vv = s[r] * 0.08838834764831845f;     // 1/sqrt(128)
                float vm = (mult != 0.f) ? vv : -1e30f;
#pragma unroll
                for (int sh = 1; sh < 16; sh <<= 1) vm = fmaxf(vm, __shfl_xor(vm, sh, 64));
                float e = mult * expf(vv - vm);
                float z = e;
#pragma unroll
                for (int sh = 1; sh < 16; sh <<= 1) z += __shfl_xor(z, sh, 64);
                sm.at.pl[trow * 20 + fr] = f2bf(e / z);
            }
        }
    }
    __syncthreads();

    // ---- PV: O[t,d] = sum_s P[t,s] * vh[s,d]  (K=16 zero-padded to 32) ----
    const ushort_t* vhB = vhbT + (size_t)(bidx * NH + h) * HD * 16;
    bf16x8 vhf[4];
#pragma unroll
    for (int n = 0; n < 4; n++) {
        bf16x8 z8 = {0, 0, 0, 0, 0, 0, 0, 0};
        if (g < 2)
            z8 = *(const bf16x8*)(vhB + (size_t)(wc + n * 16 + fr) * 16 + g * 8);
        vhf[n] = z8;
    }
#pragma unroll
    for (int m = 0; m < 4; m++) {
        bf16x8 paf = {0, 0, 0, 0, 0, 0, 0, 0};
        if (g < 2)
            paf = *(const bf16x8*)&sm.at.pl[(wr + m * 16 + fr) * 20 + g * 8];
#pragma unroll
        for (int n = 0; n < 4; n++) {
            f32x4 pv = {};
            pv = __builtin_amdgcn_mfma_f32_16x16x32_bf16(paf, vhf[n], pv, 0, 0, 0);
            int col = nb0 + wc + n * 16 + fr;
#pragma unroll
            for (int r = 0; r < 4; r++) {
                int row = mb0 + wr + m * 16 + g * 4 + r;
                obf[(size_t)row * EMB + col] = f2bf(pv[r]);
            }
        }
    }
}

// ---------------- launcher ----------------
extern "C" void kernel_launch(void* const* d_in, const int* in_sizes, int n_in,
                              void* d_out, int out_size, void* d_ws, size_t ws_size,
                              hipStream_t stream) {
    const float* q    = (const float*)d_in[0];
    const float* k    = (const float*)d_in[1];
    const float* v    = (const float*)d_in[2];
    const float* ipw  = (const float*)d_in[3];
    const float* ipb  = (const float*)d_in[4];
    const float* outw = (const float*)d_in[5];
    const float* outb = (const float*)d_in[6];
    float* out = (float*)d_out;

    int Bb = in_sizes[0] / (SEQ * EMB);     // batch (=2)
    int M  = Bb * SEQ;                      // 8192

    ushort_t* qbf  = (ushort_t*)d_ws;                  // M x EMB bf16 (16 MB)
    ushort_t* obf  = qbf + (size_t)M * EMB;            // M x EMB bf16 (16 MB)
    ushort_t* wqbf = obf + (size_t)M * EMB;            // EMB x EMB bf16 (2 MB)
    ushort_t* owbf = wqbf + (size_t)EMB * EMB;         // EMB x EMB bf16 (2 MB)
    ushort_t* khb  = owbf + (size_t)EMB * EMB;         // Bb*NH*16*HD bf16 (64 KB)
    ushort_t* vhbT = khb + (size_t)Bb * NH * 16 * HD;  // Bb*NH*HD*16 bf16 (64 KB)

    int nq = M * EMB;
    int nw = EMB * EMB;

    cvt_f32_bf16<<<dim3(nq / (256 * 8)), dim3(256), 0, stream>>>(q, qbf, nq);
    cvt_f32_bf16<<<dim3(nw / (256 * 8)), dim3(256), 0, stream>>>(ipw, wqbf, nw);   // Wq
    cvt_f32_bf16<<<dim3(nw / (256 * 8)), dim3(256), 0, stream>>>(outw, owbf, nw);
    proj_kv_small<<<dim3(Bb * 2 * 64), dim3(256), 0, stream>>>(k, v, ipw, ipb, khb, vhbT);
    gemm_qattn<<<dim3((M / BM) * (EMB / BN)), dim3(512), 0, stream>>>(
        qbf, wqbf, ipb, khb, vhbT, obf, M, EMB, EMB);
    gemm_bt_bf16<<<dim3((M / BM) * (EMB / BN)), dim3(512), 0, stream>>>(
        obf, owbf, outb, out, M, EMB, EMB);
}

// Round 8
// 90.148 us; speedup vs baseline: 3.2077x; 1.1344x over previous
//
#include <hip/hip_runtime.h>
#include <hip/hip_bf16.h>
#include <math.h>

// ---------------- problem constants ----------------
#define SEQ   4096
#define EMB   1024
#define NH    8
#define HD    128
#define NSLOT 15   // distinct gathered positions: 0..10, S-4..S-1 (+1 zero pad slot = 16)

typedef __attribute__((ext_vector_type(8))) short bf16x8;
typedef __attribute__((ext_vector_type(4))) float f32x4;
typedef __attribute__((ext_vector_type(8))) unsigned short ushort8v;
typedef __attribute__((ext_vector_type(4))) unsigned short ushort4v;
typedef unsigned short ushort_t;

// per-t slot multiplicity masks, 2 bits per slot (slot s at bits 2s..2s+1).
__device__ __constant__ unsigned int MULT[8] = {
    0x00005555u,  // t=0:   slots {0..7}
    0x10015055u,  // t=1:   {0,1,2,3,6,7,8,14}
    0x14050055u,  // t=2:   {0,1,2,3,8,9,13,14}
    0x15100055u,  // t=3:   {0,1,2,3,10,12,13,14}
    0x15800015u,  // t=S-3: {0,1,2, 11x2, 12,13,14}
    0x16800005u,  // t=S-2: {0,1, 11x2, 12x2, 13,14}
    0x1A800001u,  // t=S-1: {0, 11x2, 12x2, 13x2, 14}
    0x15400055u   // interior: {0,1,2,3,11,12,13,14}
};

__device__ __forceinline__ unsigned short f2bf(float x) {
    unsigned int u = __float_as_uint(x);
    return (unsigned short)((u + 0x7FFFu + ((u >> 16) & 1u)) >> 16);
}

__device__ __forceinline__ ushort8v pack8(float4 a, float4 b) {
    ushort8v r;
    r[0] = f2bf(a.x); r[1] = f2bf(a.y); r[2] = f2bf(a.z); r[3] = f2bf(a.w);
    r[4] = f2bf(b.x); r[5] = f2bf(b.y); r[6] = f2bf(b.z); r[7] = f2bf(b.w);
    return r;
}

// async global->LDS, 16B per lane; lds ptr must be wave-uniform
__device__ __forceinline__ void gld16(const ushort_t* g, ushort_t* l) {
    __builtin_amdgcn_global_load_lds(
        (const __attribute__((address_space(1))) unsigned int*)g,
        (__attribute__((address_space(3))) unsigned int*)l,
        16, 0, 0);
}

// bijective chunked XCD swizzle (nwg % 8 == 0)
__device__ __forceinline__ int xcd_swz(int bid, int nwg) {
    int cpx = nwg >> 3;
    return (bid & 7) * cpx + (bid >> 3);
}

// ---------------- small k/v projection (fp32): kvp[(b*2+kv)*15+slot][1024] ----------------
__global__ __launch_bounds__(256) void proj_kv_small(
    const float* __restrict__ k, const float* __restrict__ v,
    const float* __restrict__ ipw, const float* __restrict__ ipb,
    float* __restrict__ kvp) {
    int fc  = blockIdx.x & 63;
    int bkv = blockIdx.x >> 6;
    int kv  = bkv & 1;
    int b   = bkv >> 1;

    const float* x0 = (kv ? v : k) + (size_t)b * SEQ * EMB;
    const float* Wm = ipw + (size_t)(1 + kv) * EMB * EMB;
    const float* bb = ipb + (size_t)(1 + kv) * EMB;

    __shared__ __align__(16) float xs[NSLOT][EMB];
    int tid = threadIdx.x;
#pragma unroll
    for (int i = 0; i < NSLOT; i++) {
        int pos = (i < 11) ? i : (SEQ - 4 + (i - 11));
        *(float4*)&xs[i][tid * 4] = *(const float4*)&x0[(size_t)pos * EMB + tid * 4];
    }
    __syncthreads();

    if (tid < 240) {
        int row  = tid >> 4;           // slot 0..14
        int feat = fc * 16 + (tid & 15);
        const float* wrow = Wm + (size_t)feat * EMB;
        float acc = 0.f;
        for (int kk = 0; kk < EMB; kk += 4) {
            float4 xv = *(const float4*)&xs[row][kk];
            float4 wv = *(const float4*)&wrow[kk];
            acc += xv.x * wv.x + xv.y * wv.y + xv.z * wv.z + xv.w * wv.w;
        }
        kvp[((size_t)((b * 2 + kv) * NSLOT + row)) * EMB + feat] = acc + bb[feat];
    }
}

// ---------------- G[b][hs][e] = Wq_h^T kh_h[s]  (bf16),  cvec[b][hs] = bq_h . kh_h[s] ----------------
__global__ __launch_bounds__(256) void gmat(
    const float* __restrict__ kvp, const float* __restrict__ ipw,
    const float* __restrict__ ipb, ushort_t* __restrict__ G,
    float* __restrict__ cvec) {
    int hs = blockIdx.x & 127, b = blockIdx.x >> 7;
    int h = hs >> 4, s = hs & 15;
    __shared__ float xs[HD];
    __shared__ float red[HD];
    int tid = threadIdx.x;
    if (tid < HD)
        xs[tid] = (s < NSLOT)
            ? kvp[((size_t)((b * 2 + 0) * NSLOT + s)) * EMB + h * HD + tid] : 0.f;
    __syncthreads();
    int e0 = tid * 4;
    float a0 = 0.f, a1 = 0.f, a2 = 0.f, a3 = 0.f;
    for (int d = 0; d < HD; d++) {
        float xv = xs[d];
        const float* wr_ = ipw + (size_t)(h * HD + d) * EMB + e0;
        a0 += xv * wr_[0]; a1 += xv * wr_[1]; a2 += xv * wr_[2]; a3 += xv * wr_[3];
    }
    ushort4v gv; gv[0] = f2bf(a0); gv[1] = f2bf(a1); gv[2] = f2bf(a2); gv[3] = f2bf(a3);
    *(ushort4v*)&G[((size_t)b * 128 + hs) * EMB + e0] = gv;

    if (tid < HD) red[tid] = xs[tid] * ipb[h * HD + tid];
    __syncthreads();
    if (tid < 64) {
        float vsum = red[tid] + red[tid + 64];
        vsum += __shfl_down(vsum, 32, 64); vsum += __shfl_down(vsum, 16, 64);
        vsum += __shfl_down(vsum, 8, 64);  vsum += __shfl_down(vsum, 4, 64);
        vsum += __shfl_down(vsum, 2, 64);  vsum += __shfl_down(vsum, 1, 64);
        if (tid == 0) cvec[b * 128 + hs] = vsum;
    }
}

// ---------------- UT[b][e][hs] = vh_h[s] . Wo_h^T[.,e]  (bf16, transposed for MFMA B) ----------------
__global__ __launch_bounds__(256) void umat(
    const float* __restrict__ kvp, const float* __restrict__ outw,
    ushort_t* __restrict__ UT) {
    int ec = blockIdx.x & 63, b = blockIdx.x >> 6;
    __shared__ float vs[NSLOT][EMB + 4];
    int tid = threadIdx.x;
#pragma unroll
    for (int i = 0; i < NSLOT; i++)
        *(float4*)&vs[i][tid * 4] =
            *(const float4*)&kvp[((size_t)((b * 2 + 1) * NSLOT + i)) * EMB + tid * 4];
    __syncthreads();
    int half = tid >> 7, hs = tid & 127, h = hs >> 4, s = hs & 15;
    for (int ei = 0; ei < 8; ei++) {
        int e = ec * 16 + half * 8 + ei;
        float acc = 0.f;
        if (s < NSLOT) {
            const float* orow = outw + (size_t)e * EMB + h * HD;
            const float* vrow = &vs[s][h * HD];
            for (int d = 0; d < HD; d++) acc += vrow[d] * orow[d];
        }
        UT[((size_t)b * EMB + e) * 128 + hs] = f2bf(acc);
    }
}

// ---------------- scores + softmax + P:  S = q @ G^T + c, P bf16 (M x 128) ----------------
#define XBM 32
__global__ __launch_bounds__(256) void score_p(
    const float* __restrict__ q, const ushort_t* __restrict__ G,
    const float* __restrict__ cvec, ushort_t* __restrict__ P) {
    __shared__ __align__(16) union { ushort_t st[2][XBM * 64]; ushort_t p[XBM * 128]; } sm;
    int tid = threadIdx.x, lane = tid & 63, w = tid >> 6;
    int fr = lane & 15, g = lane >> 4;
    int mb0 = blockIdx.x * XBM;
    int b = mb0 >> 12;
    int srow = tid >> 3, sgr = tid & 7;
    const float* qsrc = q + (size_t)(mb0 + srow) * EMB + sgr * 8;
    int sdst = srow * 64 + ((sgr ^ (srow & 7)) << 3);

    float4 u0 = *(const float4*)(qsrc);
    float4 u1 = *(const float4*)(qsrc + 4);
    *(ushort8v*)&sm.st[0][sdst] = pack8(u0, u1);
    __syncthreads();

    const ushort_t* Gb = G + (size_t)b * 128 * EMB;
    int hsb = w * 32;                 // wave w covers heads 2w, 2w+1
    f32x4 acc[2][2] = {};
    for (int t = 0; t < 16; t++) {
        int cur = t & 1;
        float4 n0, n1;
        if (t + 1 < 16) {
            n0 = *(const float4*)(qsrc + (t + 1) * 64);
            n1 = *(const float4*)(qsrc + (t + 1) * 64 + 4);
        }
        const ushort_t* stc = sm.st[cur];
#pragma unroll
        for (int half = 0; half < 2; half++) {
            int gr_ = half * 4 + g;
            int swz = (gr_ ^ (fr & 7)) << 3;
            bf16x8 af[2], bfb[2];
#pragma unroll
            for (int m = 0; m < 2; m++)
                af[m] = *(const bf16x8*)&stc[(m * 16 + fr) * 64 + swz];
#pragma unroll
            for (int n = 0; n < 2; n++)
                bfb[n] = *(const bf16x8*)&Gb[(size_t)(hsb + n * 16 + fr) * EMB
                                             + t * 64 + half * 32 + g * 8];
#pragma unroll
            for (int m = 0; m < 2; m++)
#pragma unroll
                for (int n = 0; n < 2; n++)
                    acc[m][n] = __builtin_amdgcn_mfma_f32_16x16x32_bf16(
                        af[m], bfb[n], acc[m][n], 0, 0, 0);
        }
        if (t + 1 < 16) {
            __syncthreads();
            *(ushort8v*)&sm.st[cur ^ 1][sdst] = pack8(n0, n1);
            __syncthreads();
        }
    }
    __syncthreads();   // all st reads done before p-union overwrite

    float cv0 = cvec[b * 128 + hsb + fr];
    float cv1 = cvec[b * 128 + hsb + 16 + fr];
    const float scale = 0.08838834764831845f;   // 1/sqrt(128)
#pragma unroll
    for (int m = 0; m < 2; m++) {
#pragma unroll
        for (int r = 0; r < 4; r++) {
            int row = m * 16 + g * 4 + r;
            int tl  = (mb0 + row) & (SEQ - 1);
            int cse = (tl >= 4 && tl <= SEQ - 4) ? 7 : ((tl < 4) ? tl : tl - (SEQ - 3) + 4);
            float mult = (float)((MULT[cse] >> (fr * 2)) & 3u);
#pragma unroll
            for (int n = 0; n < 2; n++) {
                float vv = (acc[m][n][r] + (n ? cv1 : cv0)) * scale;
                float vm = (mult != 0.f) ? vv : -1e30f;
#pragma unroll
                for (int sh = 1; sh < 16; sh <<= 1) vm = fmaxf(vm, __shfl_xor(vm, sh, 64));
                float e_ = mult * expf(vv - vm);
                float z = e_;
#pragma unroll
                for (int sh = 1; sh < 16; sh <<= 1) z += __shfl_xor(z, sh, 64);
                sm.p[row * 128 + hsb + n * 16 + fr] = f2bf(e_ / z);
            }
        }
    }
    __syncthreads();
#pragma unroll
    for (int u = 0; u < 2; u++) {
        int idx = tid + u * 256;
        int row = idx >> 4, gr_ = idx & 15;
        *(ushort8v*)&P[(size_t)(mb0 + row) * 128 + gr_ * 8] =
            *(const ushort8v*)&sm.p[row * 128 + gr_ * 8];
    }
}

// ---------------- out = P(Mx128) @ UT^T(128x1024) + outb  (K=128 single-shot) ----------------
__global__ __launch_bounds__(256) void outgemm(
    const ushort_t* __restrict__ P, const ushort_t* __restrict__ UT,
    const float* __restrict__ outb, float* __restrict__ out) {
    __shared__ __align__(16) ushort_t sA[128 * 128];   // 32 KB
    __shared__ __align__(16) ushort_t sB[128 * 128];   // 32 KB
    int tid = threadIdx.x, lane = tid & 63, w = tid >> 6;
    int fr = lane & 15, g = lane >> 4;
    int lb  = xcd_swz(blockIdx.x, gridDim.x);
    int mb0 = (lb >> 3) * 128;
    int nb0 = (lb & 7) * 128;
    int b   = mb0 >> 12;
    const ushort_t* UTb = UT + (size_t)b * EMB * 128;

#pragma unroll
    for (int i = 0; i < 8; i++) {
        int flat = i * 256 + tid;
        int row = flat >> 4, gr_ = flat & 15;
        int gs = (gr_ & 8) | ((gr_ & 7) ^ (row & 7));   // pre-swizzled source granule
        gld16(P   + (size_t)(mb0 + row) * 128 + gs * 8, &sA[flat * 8]);
        gld16(UTb + (size_t)(nb0 + row) * 128 + gs * 8, &sB[flat * 8]);
    }
    __syncthreads();

    int wr = (w >> 1) * 64, wc = (w & 1) * 64;
    f32x4 acc[4][4] = {};
#pragma unroll
    for (int kk = 0; kk < 4; kk++) {
        int gr_ = kk * 4 + g;
        int swz = ((gr_ & 8) | ((gr_ & 7) ^ (fr & 7))) << 3;
        bf16x8 af[4], bfb[4];
#pragma unroll
        for (int m = 0; m < 4; m++)
            af[m] = *(const bf16x8*)&sA[(wr + m * 16 + fr) * 128 + swz];
#pragma unroll
        for (int n = 0; n < 4; n++)
            bfb[n] = *(const bf16x8*)&sB[(wc + n * 16 + fr) * 128 + swz];
#pragma unroll
        for (int m = 0; m < 4; m++)
#pragma unroll
            for (int n = 0; n < 4; n++)
                acc[m][n] = __builtin_amdgcn_mfma_f32_16x16x32_bf16(
                    af[m], bfb[n], acc[m][n], 0, 0, 0);
    }

    int rowb = mb0 + wr + g * 4, colb = nb0 + wc + fr;
#pragma unroll
    for (int n = 0; n < 4; n++) {
        int col = colb + n * 16;
        float bn = outb[col];
#pragma unroll
        for (int m = 0; m < 4; m++)
#pragma unroll
            for (int r = 0; r < 4; r++)
                out[(size_t)(rowb + m * 16 + r) * EMB + col] = acc[m][n][r] + bn;
    }
}

// ---------------- launcher ----------------
extern "C" void kernel_launch(void* const* d_in, const int* in_sizes, int n_in,
                              void* d_out, int out_size, void* d_ws, size_t ws_size,
                              hipStream_t stream) {
    const float* q    = (const float*)d_in[0];
    const float* k    = (const float*)d_in[1];
    const float* v    = (const float*)d_in[2];
    const float* ipw  = (const float*)d_in[3];
    const float* ipb  = (const float*)d_in[4];
    const float* outw = (const float*)d_in[5];
    const float* outb = (const float*)d_in[6];
    float* out = (float*)d_out;

    int Bb = in_sizes[0] / (SEQ * EMB);     // batch (=2)
    int M  = Bb * SEQ;                      // 8192

    float*    kvp  = (float*)d_ws;                               // Bb*2*15*1024 f32
    ushort_t* G    = (ushort_t*)(kvp + (size_t)Bb * 2 * NSLOT * EMB);  // Bb*128*1024 bf16
    ushort_t* UTm  = G + (size_t)Bb * 128 * EMB;                 // Bb*1024*128 bf16
    float*    cvec = (float*)(UTm + (size_t)Bb * EMB * 128);     // Bb*128 f32
    ushort_t* P    = (ushort_t*)(cvec + (size_t)Bb * 128);       // M*128 bf16

    proj_kv_small<<<dim3(Bb * 2 * 64), dim3(256), 0, stream>>>(k, v, ipw, ipb, kvp);
    gmat<<<dim3(Bb * 128), dim3(256), 0, stream>>>(kvp, ipw, ipb, G, cvec);
    umat<<<dim3(Bb * 64), dim3(256), 0, stream>>>(kvp, outw, UTm);
    score_p<<<dim3(M / XBM), dim3(256), 0, stream>>>(q, G, cvec, P);
    outgemm<<<dim3((M / 128) * (EMB / 128)), dim3(256), 0, stream>>>(P, UTm, outb, out);
}